// Round 1
// baseline (305.735 us; speedup 1.0000x reference)
//
#include <hip/hip_runtime.h>
#include <math.h>

// Performer (FAVOR+) causal attention, fp32. B=1, L=2048, D=512, H=8, DH=64, M=128.
// Pipeline: qkv gemm -> k row-sumsq + global min (atomicMin uint trick) ->
// q'/k' feature maps -> chunk outer-product sums -> in-place exclusive chunk
// prefix -> per-chunk causal kernel attention -> output gemm.

#define L       2048
#define DMODEL  512
#define NH      8
#define DH      64
#define M       128
#define CT      64          // chunk size
#define NC      (L/CT)      // 32 chunks per head
#define KEPS    1e-4f
#define DEPS    1e-6f
#define SCALE   0.2102241038134286f   // 512^-0.25
#define NCONST  0.08838834764831845f  // 128^-0.5

// workspace layout (float offsets). total = 10534913 floats = 42.1 MB
#define OFF_Q      0
#define OFF_K      1048576
#define OFF_V      2097152
#define OFF_QP     3145728          // [h][l][m]
#define OFF_KP     5242880
#define OFF_SS     7340032          // [h][c][8320]  (8192 S + 128 z), prefix in-place
#define OFF_CTX    9469952          // [l][512]
#define OFF_SUMSQ  10518528         // [h][l]
#define OFF_MINB   10534912         // 1 uint

// ---------------- GEMM: C = X @ W^T + bias, X (2048 x 512), W (512 x 512) -------------
__device__ __forceinline__ void gemm_dev(const float* __restrict__ X,
                                         const float* __restrict__ W,
                                         const float* __restrict__ bias,
                                         float* __restrict__ C)
{
    __shared__ float Xs[16][64];
    __shared__ float Ws[16][64];
    const int tid  = threadIdx.x;
    const int row0 = blockIdx.x * 64;
    const int col0 = blockIdx.y * 64;
    const int tx = tid & 15, ty = tid >> 4;
    const int lr = tid >> 2;
    const int lk = (tid & 3) << 2;
    float acc[4][4] = {{0.f}};
    for (int k0 = 0; k0 < DMODEL; k0 += 16) {
        float4 xv = *(const float4*)(X + (row0 + lr) * DMODEL + k0 + lk);
        float4 wv = *(const float4*)(W + (col0 + lr) * DMODEL + k0 + lk);
        Xs[lk+0][lr] = xv.x; Xs[lk+1][lr] = xv.y; Xs[lk+2][lr] = xv.z; Xs[lk+3][lr] = xv.w;
        Ws[lk+0][lr] = wv.x; Ws[lk+1][lr] = wv.y; Ws[lk+2][lr] = wv.z; Ws[lk+3][lr] = wv.w;
        __syncthreads();
        #pragma unroll
        for (int kk = 0; kk < 16; ++kk) {
            float4 a = *(const float4*)&Xs[kk][ty << 2];
            float4 b = *(const float4*)&Ws[kk][tx << 2];
            acc[0][0] += a.x*b.x; acc[0][1] += a.x*b.y; acc[0][2] += a.x*b.z; acc[0][3] += a.x*b.w;
            acc[1][0] += a.y*b.x; acc[1][1] += a.y*b.y; acc[1][2] += a.y*b.z; acc[1][3] += a.y*b.w;
            acc[2][0] += a.z*b.x; acc[2][1] += a.z*b.y; acc[2][2] += a.z*b.z; acc[2][3] += a.z*b.w;
            acc[3][0] += a.w*b.x; acc[3][1] += a.w*b.y; acc[3][2] += a.w*b.z; acc[3][3] += a.w*b.w;
        }
        __syncthreads();
    }
    #pragma unroll
    for (int i = 0; i < 4; ++i) {
        int r = row0 + (ty << 2) + i;
        #pragma unroll
        for (int j = 0; j < 4; ++j) {
            int c = col0 + (tx << 2) + j;
            C[r * DMODEL + c] = acc[i][j] + bias[c];
        }
    }
}

__global__ __launch_bounds__(256) void qkv_kernel(
    const float* __restrict__ xq, const float* __restrict__ xk, const float* __restrict__ xv,
    const float* __restrict__ Wq, const float* __restrict__ bq,
    const float* __restrict__ Wk, const float* __restrict__ bk,
    const float* __restrict__ Wv, const float* __restrict__ bv,
    float* __restrict__ ws)
{
    const float* X; const float* W; const float* bias; float* C;
    if (blockIdx.z == 0)      { X = xq; W = Wq; bias = bq; C = ws + OFF_Q; }
    else if (blockIdx.z == 1) { X = xk; W = Wk; bias = bk; C = ws + OFF_K; }
    else                      { X = xv; W = Wv; bias = bv; C = ws + OFF_V; }
    gemm_dev(X, W, bias, C);
}

__global__ __launch_bounds__(256) void out_gemm_kernel(
    const float* __restrict__ ctx, const float* __restrict__ Wo,
    const float* __restrict__ bo, float* __restrict__ out)
{
    gemm_dev(ctx, Wo, bo, out);
}

// ---------------- init + per-row sumsq of K + global min --------------------
__global__ void init_kernel(unsigned int* minb) { *minb = 0x7f7fffffu; }

__global__ __launch_bounds__(256) void rowss_kernel(
    const float* __restrict__ Kmat, float* __restrict__ sumsq, unsigned int* __restrict__ minb)
{
    const int wave = threadIdx.x >> 6;
    const int lane = threadIdx.x & 63;
    const int l = blockIdx.x * 4 + wave;
    float mn = 3.4e38f;
    #pragma unroll
    for (int h = 0; h < NH; ++h) {
        float x = Kmat[l * DMODEL + h * DH + lane];
        float ss = x * x;
        #pragma unroll
        for (int off = 32; off >= 1; off >>= 1) ss += __shfl_xor(ss, off, 64);
        if (lane == 0) sumsq[h * L + l] = ss;
        mn = fminf(mn, ss);
    }
    if (lane == 0) atomicMin(minb, __float_as_uint(mn));
}

// ---------------- q' / k' feature maps --------------------------------------
__global__ __launch_bounds__(128) void primes_kernel(
    const float* __restrict__ Q, const float* __restrict__ Kmat,
    const float* __restrict__ RF, const float* __restrict__ sumsq,
    const unsigned int* __restrict__ minb,
    float* __restrict__ QP, float* __restrict__ KP)
{
    __shared__ float RFs[DH * M];
    __shared__ float qs[DH], ks[DH];
    const int tid = threadIdx.x;             // m index
    const int h  = blockIdx.y;
    const int l0 = blockIdx.x * 16;
    for (int i = tid * 4; i < DH * M; i += 512)
        *(float4*)&RFs[i] = *(const float4*)&RF[i];
    const float s2 = SCALE * SCALE;
    const float kst = -0.5f * s2 * __uint_as_float(*minb);   // global k stabilizer
    for (int li = 0; li < 16; ++li) {
        const int l = l0 + li;
        __syncthreads();
        if (tid < 64)  qs[tid]      = SCALE * Q[l * DMODEL + h * DH + tid];
        else           ks[tid - 64] = SCALE * Kmat[l * DMODEL + h * DH + (tid - 64)];
        __syncthreads();
        float pq = 0.f, pk = 0.f;
        #pragma unroll 8
        for (int d = 0; d < DH; ++d) {
            float rf = RFs[d * M + tid];
            pq += qs[d] * rf;
            pk += ks[d] * rf;
        }
        const float hk = -0.5f * s2 * sumsq[h * L + l];
        const int base = (h * L + l) * M + tid;
        QP[base] = NCONST * (expf(pq) + KEPS);              // q_stab == h_q cancels
        KP[base] = NCONST * (expf(hk - kst + pk) + KEPS);
    }
}

// ---------------- chunk outer-product sums: S_c = K'^T V, z_c = sum k' ------
__global__ __launch_bounds__(256) void chunksum_kernel(
    const float* __restrict__ KP, const float* __restrict__ V, float* __restrict__ SS)
{
    __shared__ float kp[16][M];
    __shared__ float vs[16][DH];
    const int tid = threadIdx.x;
    const int c = blockIdx.x, h = blockIdx.y;
    const int d  = tid & 63;
    const int mg = tid >> 6;                  // 0..3 -> m block of 32
    float4 acc[8];
    #pragma unroll
    for (int g = 0; g < 8; ++g) acc[g] = make_float4(0.f, 0.f, 0.f, 0.f);
    float zacc = 0.f;
    for (int t0 = 0; t0 < CT; t0 += 16) {
        for (int p = tid; p < 512; p += 256) {            // 16x128 floats as float4
            int r = p >> 5, mc = (p & 31) << 2;
            *(float4*)&kp[r][mc] = *(const float4*)&KP[((h * L) + c * CT + t0 + r) * M + mc];
        }
        {   int p = tid & 255;                            // 16x64 floats as float4
            if (p < 256) {
                int r = p >> 4, dc = (p & 15) << 2;
                *(float4*)&vs[r][dc] = *(const float4*)&V[(c * CT + t0 + r) * DMODEL + h * DH + dc];
            }
        }
        __syncthreads();
        #pragma unroll
        for (int ll = 0; ll < 16; ++ll) {
            float vd = vs[ll][d];
            const float4* krow = (const float4*)&kp[ll][mg * 32];
            #pragma unroll
            for (int g = 0; g < 8; ++g) {
                float4 kv = krow[g];
                acc[g].x += kv.x * vd; acc[g].y += kv.y * vd;
                acc[g].z += kv.z * vd; acc[g].w += kv.w * vd;
            }
            if (tid < M) zacc += kp[ll][tid];
        }
        __syncthreads();
    }
    float* out = SS + (h * NC + c) * 8320;
    #pragma unroll
    for (int g = 0; g < 8; ++g) {
        int m = mg * 32 + g * 4;
        out[(m+0) * DH + d] = acc[g].x;
        out[(m+1) * DH + d] = acc[g].y;
        out[(m+2) * DH + d] = acc[g].z;
        out[(m+3) * DH + d] = acc[g].w;
    }
    if (tid < M) out[8192 + tid] = zacc;
}

// ---------------- in-place exclusive prefix over chunks ---------------------
__global__ __launch_bounds__(256) void prefix_kernel(float* __restrict__ S)
{
    const int h = blockIdx.y;
    const int idx = blockIdx.x * 256 + threadIdx.x;
    if (idx >= 8320) return;
    float run = 0.f;
    for (int c = 0; c < NC; ++c) {
        float* p = S + (h * NC + c) * 8320 + idx;
        float v = *p;
        *p = run;
        run += v;
    }
}

// ---------------- per-chunk causal kernel attention -------------------------
__global__ __launch_bounds__(256) void attn_kernel(
    const float* __restrict__ QP, const float* __restrict__ KP,
    const float* __restrict__ V, const float* __restrict__ SP,
    float* __restrict__ ctx)
{
    __shared__ float qp[CT][M];
    __shared__ float kp[CT][M];
    __shared__ float vs[CT][DH];
    __shared__ float A[CT][CT];
    __shared__ float Ns[CT][DH];
    __shared__ float den[CT];
    __shared__ float zp[M];
    const int tid = threadIdx.x;
    const int c = blockIdx.x, h = blockIdx.y;
    const float* sp = SP + (h * NC + c) * 8320;
    for (int p = tid; p < 2048; p += 256) {               // 64x128 as float4 (x2)
        int r = p >> 5, mc = (p & 31) << 2;
        int g = ((h * L) + c * CT + r) * M + mc;
        *(float4*)&qp[r][mc] = *(const float4*)&QP[g];
        *(float4*)&kp[r][mc] = *(const float4*)&KP[g];
    }
    for (int p = tid; p < 1024; p += 256) {               // 64x64 as float4
        int r = p >> 4, dc = (p & 15) << 2;
        *(float4*)&vs[r][dc] = *(const float4*)&V[(c * CT + r) * DMODEL + h * DH + dc];
    }
    if (tid < M) zp[tid] = sp[8192 + tid];
    __syncthreads();
    const int tx = tid & 15, ty = tid >> 4;
    // scores A = Q' K'^T over m (K=128)
    {
        float a4[4][4] = {{0.f}};
        #pragma unroll 4
        for (int m4 = 0; m4 < 32; ++m4) {
            float4 qa[4], kb[4];
            #pragma unroll
            for (int ii = 0; ii < 4; ++ii) qa[ii] = *(const float4*)&qp[(ty<<2)+ii][m4<<2];
            #pragma unroll
            for (int jj = 0; jj < 4; ++jj) kb[jj] = *(const float4*)&kp[(tx<<2)+jj][m4<<2];
            #pragma unroll
            for (int ii = 0; ii < 4; ++ii)
                #pragma unroll
                for (int jj = 0; jj < 4; ++jj)
                    a4[ii][jj] += qa[ii].x*kb[jj].x + qa[ii].y*kb[jj].y
                                + qa[ii].z*kb[jj].z + qa[ii].w*kb[jj].w;
        }
        #pragma unroll
        for (int ii = 0; ii < 4; ++ii)
            #pragma unroll
            for (int jj = 0; jj < 4; ++jj)
                A[(ty<<2)+ii][(tx<<2)+jj] = a4[ii][jj];
    }
    // N0 = Q' @ S_prefix (K=128), den0 = Q' @ z_prefix
    {
        float n4[4][4] = {{0.f}};
        float d4[4] = {0.f};
        for (int m = 0; m < M; ++m) {
            float4 spv = *(const float4*)&sp[m * DH + (tx << 2)];
            float zv = zp[m];
            #pragma unroll
            for (int ii = 0; ii < 4; ++ii) {
                float qv = qp[(ty<<2)+ii][m];
                n4[ii][0] += qv * spv.x; n4[ii][1] += qv * spv.y;
                n4[ii][2] += qv * spv.z; n4[ii][3] += qv * spv.w;
                d4[ii] += qv * zv;
            }
        }
        #pragma unroll
        for (int ii = 0; ii < 4; ++ii) {
            #pragma unroll
            for (int jj = 0; jj < 4; ++jj) Ns[(ty<<2)+ii][(tx<<2)+jj] = n4[ii][jj];
            if (tx == 0) den[(ty<<2)+ii] = d4[ii];
        }
    }
    __syncthreads();
    // finalize: causal within-chunk accumulation + divide
    {
        const int d = tid & 63;
        const int lg = tid >> 6;
        for (int li = 0; li < 16; ++li) {
            int l = lg * 16 + li;
            float accn = Ns[l][d];
            float accd = den[l];
            for (int j = 0; j <= l; ++j) {
                float a = A[l][j];
                accn += a * vs[j][d];
                accd += a;
            }
            ctx[(c * CT + l) * DMODEL + h * DH + d] = accn / (accd + DEPS);
        }
    }
}

extern "C" void kernel_launch(void* const* d_in, const int* in_sizes, int n_in,
                              void* d_out, int out_size, void* d_ws, size_t ws_size,
                              hipStream_t stream)
{
    const float* query = (const float*)d_in[0];
    const float* key_  = (const float*)d_in[1];
    const float* value = (const float*)d_in[2];
    const float* Wq = (const float*)d_in[3];
    const float* bq = (const float*)d_in[4];
    const float* Wk = (const float*)d_in[5];
    const float* bk = (const float*)d_in[6];
    const float* Wv = (const float*)d_in[7];
    const float* bv = (const float*)d_in[8];
    const float* Wo = (const float*)d_in[9];
    const float* bo = (const float*)d_in[10];
    const float* RF = (const float*)d_in[11];

    float* ws = (float*)d_ws;
    float* Q    = ws + OFF_Q;
    float* K    = ws + OFF_K;
    float* V    = ws + OFF_V;
    float* QP   = ws + OFF_QP;
    float* KP   = ws + OFF_KP;
    float* SS   = ws + OFF_SS;
    float* CTX  = ws + OFF_CTX;
    float* SUMSQ = ws + OFF_SUMSQ;
    unsigned int* MINB = (unsigned int*)(ws + OFF_MINB);

    qkv_kernel<<<dim3(32, 8, 3), 256, 0, stream>>>(query, key_, value,
                                                   Wq, bq, Wk, bk, Wv, bv, ws);
    init_kernel<<<1, 1, 0, stream>>>(MINB);
    rowss_kernel<<<512, 256, 0, stream>>>(K, SUMSQ, MINB);
    primes_kernel<<<dim3(128, 8), 128, 0, stream>>>(Q, K, RF, SUMSQ, MINB, QP, KP);
    chunksum_kernel<<<dim3(NC, 8), 256, 0, stream>>>(KP, V, SS);
    prefix_kernel<<<dim3(33, 8), 256, 0, stream>>>(SS);
    attn_kernel<<<dim3(NC, 8), 256, 0, stream>>>(QP, KP, V, SS, CTX);
    out_gemm_kernel<<<dim3(32, 8), 256, 0, stream>>>(CTX, Wo, bo, (float*)d_out);
}

// Round 2
// 291.605 us; speedup vs baseline: 1.0485x; 1.0485x over previous
//
#include <hip/hip_runtime.h>
#include <math.h>

// Performer (FAVOR+) causal attention. B=1, L=2048, D=512, H=8, DH=64, M=128.
// Round 2: projection GEMMs moved to bf16 MFMA (16x16x32), fp32 accumulate.
// fp32->bf16 conversion fused into GEMM staging; attn writes bf16 context.

#define L       2048
#define DMODEL  512
#define NH      8
#define DH      64
#define M       128
#define CT      64          // chunk size
#define NC      (L/CT)      // 32 chunks per head
#define KEPS    1e-4f
#define DEPS    1e-6f
#define SCALE   0.2102241038134286f   // 512^-0.25
#define NCONST  0.08838834764831845f  // 128^-0.5

// workspace layout (float offsets), same as round 1 (42.1 MB)
#define OFF_Q      0
#define OFF_K      1048576
#define OFF_V      2097152
#define OFF_QP     3145728          // [h][l][m]
#define OFF_KP     5242880
#define OFF_SS     7340032          // [h][c][8320]  (8192 S + 128 z), prefix in-place
#define OFF_CTX    9469952          // bf16 [l][512] (ushort, half the region used)
#define OFF_SUMSQ  10518528         // [h][l]
#define OFF_MINB   10534912         // 1 uint

typedef short bf16x8 __attribute__((ext_vector_type(8)));
typedef float f32x4  __attribute__((ext_vector_type(4)));

__device__ __forceinline__ unsigned short f2bf(float f) {
    unsigned u = __float_as_uint(f);
    return (unsigned short)((u + 0x7fffu + ((u >> 16) & 1u)) >> 16);
}
__device__ __forceinline__ unsigned pack2(float a, float b) {
    return (unsigned)f2bf(a) | ((unsigned)f2bf(b) << 16);
}

// ---------------- bf16 MFMA GEMM: C = A @ W^T + bias ------------------------
// A: rows x 512 (bf16 if A_BF16 else fp32), W: cols x 512 fp32 (cast inline).
// 128x128 tile / block, 256 threads (4 waves in 2x2), K-chunk 32.
// LDS layout [k8][m][8] bf16 so MFMA A/B frags are single ds_read_b128.
template<bool A_BF16>
__device__ __forceinline__ void gemm_bt_mfma(const void* __restrict__ Ap,
                                             const float* __restrict__ Wf,
                                             const float* __restrict__ bias,
                                             float* __restrict__ C)
{
    __shared__ uint4 As8[512];   // 8 KB: A tile 128x32 bf16
    __shared__ uint4 Bs8[512];   // 8 KB: B tile 128x32 bf16
    const int tid  = threadIdx.x;
    const int lane = tid & 63;
    const int wave = tid >> 6;
    const int wm = wave >> 1, wn = wave & 1;
    const int row0 = blockIdx.x * 128;
    const int col0 = blockIdx.y * 128;
    const int quad = lane >> 4;
    const int l15  = lane & 15;
    const int m0  = tid & 127;
    const int k80 = tid >> 7;        // slot t=0
    const int k81 = k80 + 2;         // slot t=1 (tid+256)

    f32x4 acc[4][4];
    const f32x4 z4 = {0.f, 0.f, 0.f, 0.f};
    #pragma unroll
    for (int i = 0; i < 4; ++i)
        #pragma unroll
        for (int j = 0; j < 4; ++j) acc[i][j] = z4;

    uint4 ra[2], rb[2];
    auto loadA = [&](int ck, uint4* r) {
        if (A_BF16) {
            const uint4* Ag = (const uint4*)Ap;
            r[0] = Ag[(row0 + m0) * (DMODEL / 8) + ck * 4 + k80];
            r[1] = Ag[(row0 + m0) * (DMODEL / 8) + ck * 4 + k81];
        } else {
            const float* Af = (const float*)Ap;
            #pragma unroll
            for (int t = 0; t < 2; ++t) {
                int k8 = t ? k81 : k80;
                const float4* gp = (const float4*)&Af[(row0 + m0) * DMODEL + ck * 32 + k8 * 8];
                float4 v0 = gp[0], v1 = gp[1];
                r[t] = make_uint4(pack2(v0.x, v0.y), pack2(v0.z, v0.w),
                                  pack2(v1.x, v1.y), pack2(v1.z, v1.w));
            }
        }
    };
    auto loadB = [&](int ck, uint4* r) {
        #pragma unroll
        for (int t = 0; t < 2; ++t) {
            int k8 = t ? k81 : k80;
            const float4* gp = (const float4*)&Wf[(col0 + m0) * DMODEL + ck * 32 + k8 * 8];
            float4 v0 = gp[0], v1 = gp[1];
            r[t] = make_uint4(pack2(v0.x, v0.y), pack2(v0.z, v0.w),
                              pack2(v1.x, v1.y), pack2(v1.z, v1.w));
        }
    };

    loadA(0, ra); loadB(0, rb);
    for (int ck = 0; ck < 16; ++ck) {
        __syncthreads();
        As8[k80 * 128 + m0] = ra[0]; As8[k81 * 128 + m0] = ra[1];
        Bs8[k80 * 128 + m0] = rb[0]; Bs8[k81 * 128 + m0] = rb[1];
        __syncthreads();
        if (ck < 15) { loadA(ck + 1, ra); loadB(ck + 1, rb); }
        const bf16x8* Av = (const bf16x8*)As8;
        const bf16x8* Bv = (const bf16x8*)Bs8;
        bf16x8 af[4], bfr[4];
        #pragma unroll
        for (int i = 0; i < 4; ++i) af[i]  = Av[quad * 128 + wm * 64 + i * 16 + l15];
        #pragma unroll
        for (int j = 0; j < 4; ++j) bfr[j] = Bv[quad * 128 + wn * 64 + j * 16 + l15];
        #pragma unroll
        for (int i = 0; i < 4; ++i)
            #pragma unroll
            for (int j = 0; j < 4; ++j)
                acc[i][j] = __builtin_amdgcn_mfma_f32_16x16x32_bf16(af[i], bfr[j], acc[i][j], 0, 0, 0);
    }
    // epilogue: C/D frag mapping col=lane&15, row=(lane>>4)*4+reg
    #pragma unroll
    for (int i = 0; i < 4; ++i)
        #pragma unroll
        for (int j = 0; j < 4; ++j) {
            int c = col0 + wn * 64 + j * 16 + l15;
            float bv_ = bias[c];
            #pragma unroll
            for (int reg = 0; reg < 4; ++reg) {
                int r = row0 + wm * 64 + i * 16 + quad * 4 + reg;
                C[r * DMODEL + c] = acc[i][j][reg] + bv_;
            }
        }
}

__global__ __launch_bounds__(256) void qkv_mfma_kernel(
    const float* __restrict__ xq, const float* __restrict__ xk, const float* __restrict__ xv,
    const float* __restrict__ Wq, const float* __restrict__ bq,
    const float* __restrict__ Wk, const float* __restrict__ bk,
    const float* __restrict__ Wv, const float* __restrict__ bv,
    float* __restrict__ ws)
{
    const float* X; const float* W; const float* bias; float* C;
    if (blockIdx.z == 0)      { X = xq; W = Wq; bias = bq; C = ws + OFF_Q; }
    else if (blockIdx.z == 1) { X = xk; W = Wk; bias = bk; C = ws + OFF_K; }
    else                      { X = xv; W = Wv; bias = bv; C = ws + OFF_V; }
    gemm_bt_mfma<false>(X, W, bias, C);
}

__global__ __launch_bounds__(256) void out_gemm_kernel(
    const unsigned short* __restrict__ ctxb, const float* __restrict__ Wo,
    const float* __restrict__ bo, float* __restrict__ out)
{
    gemm_bt_mfma<true>(ctxb, Wo, bo, out);
}

// ---------------- init + per-row sumsq of K + global min --------------------
__global__ void init_kernel(unsigned int* minb) { *minb = 0x7f7fffffu; }

__global__ __launch_bounds__(256) void rowss_kernel(
    const float* __restrict__ Kmat, float* __restrict__ sumsq, unsigned int* __restrict__ minb)
{
    const int wave = threadIdx.x >> 6;
    const int lane = threadIdx.x & 63;
    const int l = blockIdx.x * 4 + wave;
    float mn = 3.4e38f;
    #pragma unroll
    for (int h = 0; h < NH; ++h) {
        float x = Kmat[l * DMODEL + h * DH + lane];
        float ss = x * x;
        #pragma unroll
        for (int off = 32; off >= 1; off >>= 1) ss += __shfl_xor(ss, off, 64);
        if (lane == 0) sumsq[h * L + l] = ss;
        mn = fminf(mn, ss);
    }
    if (lane == 0) atomicMin(minb, __float_as_uint(mn));
}

// ---------------- q' / k' feature maps --------------------------------------
__global__ __launch_bounds__(128) void primes_kernel(
    const float* __restrict__ Q, const float* __restrict__ Kmat,
    const float* __restrict__ RF, const float* __restrict__ sumsq,
    const unsigned int* __restrict__ minb,
    float* __restrict__ QP, float* __restrict__ KP)
{
    __shared__ float RFs[DH * M];
    __shared__ float qs[DH], ks[DH];
    const int tid = threadIdx.x;             // m index
    const int h  = blockIdx.y;
    const int l0 = blockIdx.x * 16;
    for (int i = tid * 4; i < DH * M; i += 512)
        *(float4*)&RFs[i] = *(const float4*)&RF[i];
    const float s2 = SCALE * SCALE;
    const float kst = -0.5f * s2 * __uint_as_float(*minb);   // global k stabilizer
    for (int li = 0; li < 16; ++li) {
        const int l = l0 + li;
        __syncthreads();
        if (tid < 64)  qs[tid]      = SCALE * Q[l * DMODEL + h * DH + tid];
        else           ks[tid - 64] = SCALE * Kmat[l * DMODEL + h * DH + (tid - 64)];
        __syncthreads();
        float pq = 0.f, pk = 0.f;
        #pragma unroll 8
        for (int d = 0; d < DH; ++d) {
            float rf = RFs[d * M + tid];
            pq += qs[d] * rf;
            pk += ks[d] * rf;
        }
        const float hk = -0.5f * s2 * sumsq[h * L + l];
        const int base = (h * L + l) * M + tid;
        QP[base] = NCONST * (expf(pq) + KEPS);              // q_stab == h_q cancels
        KP[base] = NCONST * (expf(hk - kst + pk) + KEPS);
    }
}

// ---------------- chunk outer-product sums: S_c = K'^T V, z_c = sum k' ------
__global__ __launch_bounds__(256) void chunksum_kernel(
    const float* __restrict__ KP, const float* __restrict__ V, float* __restrict__ SS)
{
    __shared__ float kp[16][M];
    __shared__ float vs[16][DH];
    const int tid = threadIdx.x;
    const int c = blockIdx.x, h = blockIdx.y;
    const int d  = tid & 63;
    const int mg = tid >> 6;                  // 0..3 -> m block of 32
    float4 acc[8];
    #pragma unroll
    for (int g = 0; g < 8; ++g) acc[g] = make_float4(0.f, 0.f, 0.f, 0.f);
    float zacc = 0.f;
    for (int t0 = 0; t0 < CT; t0 += 16) {
        for (int p = tid; p < 512; p += 256) {            // 16x128 floats as float4
            int r = p >> 5, mc = (p & 31) << 2;
            *(float4*)&kp[r][mc] = *(const float4*)&KP[((h * L) + c * CT + t0 + r) * M + mc];
        }
        {   int p = tid & 255;                            // 16x64 floats as float4
            if (p < 256) {
                int r = p >> 4, dc = (p & 15) << 2;
                *(float4*)&vs[r][dc] = *(const float4*)&V[(c * CT + t0 + r) * DMODEL + h * DH + dc];
            }
        }
        __syncthreads();
        #pragma unroll
        for (int ll = 0; ll < 16; ++ll) {
            float vd = vs[ll][d];
            const float4* krow = (const float4*)&kp[ll][mg * 32];
            #pragma unroll
            for (int g = 0; g < 8; ++g) {
                float4 kv = krow[g];
                acc[g].x += kv.x * vd; acc[g].y += kv.y * vd;
                acc[g].z += kv.z * vd; acc[g].w += kv.w * vd;
            }
            if (tid < M) zacc += kp[ll][tid];
        }
        __syncthreads();
    }
    float* out = SS + (h * NC + c) * 8320;
    #pragma unroll
    for (int g = 0; g < 8; ++g) {
        int m = mg * 32 + g * 4;
        out[(m+0) * DH + d] = acc[g].x;
        out[(m+1) * DH + d] = acc[g].y;
        out[(m+2) * DH + d] = acc[g].z;
        out[(m+3) * DH + d] = acc[g].w;
    }
    if (tid < M) out[8192 + tid] = zacc;
}

// ---------------- in-place exclusive prefix over chunks ---------------------
__global__ __launch_bounds__(256) void prefix_kernel(float* __restrict__ S)
{
    const int h = blockIdx.y;
    const int idx = blockIdx.x * 256 + threadIdx.x;
    if (idx >= 8320) return;
    float run = 0.f;
    for (int c = 0; c < NC; ++c) {
        float* p = S + (h * NC + c) * 8320 + idx;
        float v = *p;
        *p = run;
        run += v;
    }
}

// ---------------- per-chunk causal kernel attention -------------------------
__global__ __launch_bounds__(256) void attn_kernel(
    const float* __restrict__ QP, const float* __restrict__ KP,
    const float* __restrict__ V, const float* __restrict__ SP,
    unsigned short* __restrict__ ctxb)
{
    __shared__ float qp[CT][M];
    __shared__ float kp[CT][M];
    __shared__ float vs[CT][DH];
    __shared__ float A[CT][CT];
    __shared__ float Ns[CT][DH];
    __shared__ float den[CT];
    __shared__ float zp[M];
    const int tid = threadIdx.x;
    const int c = blockIdx.x, h = blockIdx.y;
    const float* sp = SP + (h * NC + c) * 8320;
    for (int p = tid; p < 2048; p += 256) {               // 64x128 as float4 (x2)
        int r = p >> 5, mc = (p & 31) << 2;
        int g = ((h * L) + c * CT + r) * M + mc;
        *(float4*)&qp[r][mc] = *(const float4*)&QP[g];
        *(float4*)&kp[r][mc] = *(const float4*)&KP[g];
    }
    for (int p = tid; p < 1024; p += 256) {               // 64x64 as float4
        int r = p >> 4, dc = (p & 15) << 2;
        *(float4*)&vs[r][dc] = *(const float4*)&V[(c * CT + r) * DMODEL + h * DH + dc];
    }
    if (tid < M) zp[tid] = sp[8192 + tid];
    __syncthreads();
    const int tx = tid & 15, ty = tid >> 4;
    // scores A = Q' K'^T over m (K=128)
    {
        float a4[4][4] = {{0.f}};
        #pragma unroll 4
        for (int m4 = 0; m4 < 32; ++m4) {
            float4 qa[4], kb[4];
            #pragma unroll
            for (int ii = 0; ii < 4; ++ii) qa[ii] = *(const float4*)&qp[(ty<<2)+ii][m4<<2];
            #pragma unroll
            for (int jj = 0; jj < 4; ++jj) kb[jj] = *(const float4*)&kp[(tx<<2)+jj][m4<<2];
            #pragma unroll
            for (int ii = 0; ii < 4; ++ii)
                #pragma unroll
                for (int jj = 0; jj < 4; ++jj)
                    a4[ii][jj] += qa[ii].x*kb[jj].x + qa[ii].y*kb[jj].y
                                + qa[ii].z*kb[jj].z + qa[ii].w*kb[jj].w;
        }
        #pragma unroll
        for (int ii = 0; ii < 4; ++ii)
            #pragma unroll
            for (int jj = 0; jj < 4; ++jj)
                A[(ty<<2)+ii][(tx<<2)+jj] = a4[ii][jj];
    }
    // N0 = Q' @ S_prefix (K=128), den0 = Q' @ z_prefix
    {
        float n4[4][4] = {{0.f}};
        float d4[4] = {0.f};
        for (int m = 0; m < M; ++m) {
            float4 spv = *(const float4*)&sp[m * DH + (tx << 2)];
            float zv = zp[m];
            #pragma unroll
            for (int ii = 0; ii < 4; ++ii) {
                float qv = qp[(ty<<2)+ii][m];
                n4[ii][0] += qv * spv.x; n4[ii][1] += qv * spv.y;
                n4[ii][2] += qv * spv.z; n4[ii][3] += qv * spv.w;
                d4[ii] += qv * zv;
            }
        }
        #pragma unroll
        for (int ii = 0; ii < 4; ++ii) {
            #pragma unroll
            for (int jj = 0; jj < 4; ++jj) Ns[(ty<<2)+ii][(tx<<2)+jj] = n4[ii][jj];
            if (tx == 0) den[(ty<<2)+ii] = d4[ii];
        }
    }
    __syncthreads();
    // finalize: causal within-chunk accumulation + divide, write bf16
    {
        const int d = tid & 63;
        const int lg = tid >> 6;
        for (int li = 0; li < 16; ++li) {
            int l = lg * 16 + li;
            float accn = Ns[l][d];
            float accd = den[l];
            for (int j = 0; j <= l; ++j) {
                float a = A[l][j];
                accn += a * vs[j][d];
                accd += a;
            }
            ctxb[(c * CT + l) * DMODEL + h * DH + d] = f2bf(accn / (accd + DEPS));
        }
    }
}

extern "C" void kernel_launch(void* const* d_in, const int* in_sizes, int n_in,
                              void* d_out, int out_size, void* d_ws, size_t ws_size,
                              hipStream_t stream)
{
    const float* query = (const float*)d_in[0];
    const float* key_  = (const float*)d_in[1];
    const float* value = (const float*)d_in[2];
    const float* Wq = (const float*)d_in[3];
    const float* bq = (const float*)d_in[4];
    const float* Wk = (const float*)d_in[5];
    const float* bk = (const float*)d_in[6];
    const float* Wv = (const float*)d_in[7];
    const float* bv = (const float*)d_in[8];
    const float* Wo = (const float*)d_in[9];
    const float* bo = (const float*)d_in[10];
    const float* RF = (const float*)d_in[11];

    float* ws = (float*)d_ws;
    float* Q    = ws + OFF_Q;
    float* K    = ws + OFF_K;
    float* V    = ws + OFF_V;
    float* QP   = ws + OFF_QP;
    float* KP   = ws + OFF_KP;
    float* SS   = ws + OFF_SS;
    unsigned short* CTXB = (unsigned short*)(ws + OFF_CTX);
    float* SUMSQ = ws + OFF_SUMSQ;
    unsigned int* MINB = (unsigned int*)(ws + OFF_MINB);

    qkv_mfma_kernel<<<dim3(16, 4, 3), 256, 0, stream>>>(query, key_, value,
                                                        Wq, bq, Wk, bk, Wv, bv, ws);
    init_kernel<<<1, 1, 0, stream>>>(MINB);
    rowss_kernel<<<512, 256, 0, stream>>>(K, SUMSQ, MINB);
    primes_kernel<<<dim3(128, 8), 128, 0, stream>>>(Q, K, RF, SUMSQ, MINB, QP, KP);
    chunksum_kernel<<<dim3(NC, 8), 256, 0, stream>>>(KP, V, SS);
    prefix_kernel<<<dim3(33, 8), 256, 0, stream>>>(SS);
    attn_kernel<<<dim3(NC, 8), 256, 0, stream>>>(QP, KP, V, SS, CTXB);
    out_gemm_kernel<<<dim3(16, 4), 256, 0, stream>>>(CTXB, Wo, bo, (float*)d_out);
}

// Round 3
// 218.724 us; speedup vs baseline: 1.3978x; 1.3332x over previous
//
#include <hip/hip_runtime.h>
#include <math.h>

// Performer (FAVOR+) causal attention. B=1, L=2048, D=512, H=8, DH=64, M=128.
// Round 3: attn restructured as MFMA (scores + masked-A @ [V;S]), bf16
// intermediates everywhere, chunksum writes S^T, workspace 25.4 MB.

#define L       2048
#define DMODEL  512
#define NH      8
#define DH      64
#define M       128
#define CT      64          // chunk size
#define NC      (L/CT)      // 32 chunks per head
#define KEPS    1e-4f
#define DEPS    1e-6f
#define SCALE   0.2102241038134286f   // 512^-0.25
#define NCONST  0.08838834764831845f  // 128^-0.5

// workspace layout (float offsets). total = 6340609 floats = 25.4 MB
#define OFF_QB     0          // bf16 [l][512]
#define OFF_KB     524288
#define OFF_VB     1048576
#define OFF_QPB    1572864    // bf16 [h][l][m]
#define OFF_KPB    2621440
#define OFF_SS     3670016    // fp32 [h][c][ d*M + m ] (+z at 8192), 8320 per (h,c)
#define OFF_CTX    5799936    // bf16 [l][512]
#define OFF_SUMSQ  6324224    // fp32 [h][l]
#define OFF_MINB   6340608    // 1 uint

typedef short bf16x8 __attribute__((ext_vector_type(8)));
typedef float f32x4  __attribute__((ext_vector_type(4)));
typedef unsigned short ushort_t;

__device__ __forceinline__ ushort_t f2bf(float f) {
    unsigned u = __float_as_uint(f);
    return (ushort_t)((u + 0x7fffu + ((u >> 16) & 1u)) >> 16);
}
__device__ __forceinline__ float bf2f(ushort_t u) {
    return __uint_as_float(((unsigned)u) << 16);
}
__device__ __forceinline__ unsigned pack2(float a, float b) {
    return (unsigned)f2bf(a) | ((unsigned)f2bf(b) << 16);
}
__device__ __forceinline__ void unpack8(uint4 u, float* d) {
    d[0] = bf2f(u.x & 0xffff); d[1] = bf2f(u.x >> 16);
    d[2] = bf2f(u.y & 0xffff); d[3] = bf2f(u.y >> 16);
    d[4] = bf2f(u.z & 0xffff); d[5] = bf2f(u.z >> 16);
    d[6] = bf2f(u.w & 0xffff); d[7] = bf2f(u.w >> 16);
}

// ---------------- bf16 MFMA GEMM: C = A @ W^T + bias ------------------------
// 128x128 tile / block, 256 threads (4 waves 2x2), K-chunk 32.
template<bool A_BF16, bool C_BF16>
__device__ __forceinline__ void gemm_bt_mfma(const void* __restrict__ Ap,
                                             const float* __restrict__ Wf,
                                             const float* __restrict__ bias,
                                             void* __restrict__ Cp)
{
    __shared__ uint4 As8[512];   // 8 KB: A tile 128x32 bf16
    __shared__ uint4 Bs8[512];   // 8 KB: B tile 128x32 bf16
    const int tid  = threadIdx.x;
    const int lane = tid & 63;
    const int wave = tid >> 6;
    const int wm = wave >> 1, wn = wave & 1;
    const int row0 = blockIdx.x * 128;
    const int col0 = blockIdx.y * 128;
    const int quad = lane >> 4;
    const int l15  = lane & 15;
    const int m0  = tid & 127;
    const int k80 = tid >> 7;
    const int k81 = k80 + 2;

    f32x4 acc[4][4];
    const f32x4 z4 = {0.f, 0.f, 0.f, 0.f};
    #pragma unroll
    for (int i = 0; i < 4; ++i)
        #pragma unroll
        for (int j = 0; j < 4; ++j) acc[i][j] = z4;

    uint4 ra[2], rb[2];
    auto loadA = [&](int ck, uint4* r) {
        if (A_BF16) {
            const uint4* Ag = (const uint4*)Ap;
            r[0] = Ag[(row0 + m0) * (DMODEL / 8) + ck * 4 + k80];
            r[1] = Ag[(row0 + m0) * (DMODEL / 8) + ck * 4 + k81];
        } else {
            const float* Af = (const float*)Ap;
            #pragma unroll
            for (int t = 0; t < 2; ++t) {
                int k8 = t ? k81 : k80;
                const float4* gp = (const float4*)&Af[(row0 + m0) * DMODEL + ck * 32 + k8 * 8];
                float4 v0 = gp[0], v1 = gp[1];
                r[t] = make_uint4(pack2(v0.x, v0.y), pack2(v0.z, v0.w),
                                  pack2(v1.x, v1.y), pack2(v1.z, v1.w));
            }
        }
    };
    auto loadB = [&](int ck, uint4* r) {
        #pragma unroll
        for (int t = 0; t < 2; ++t) {
            int k8 = t ? k81 : k80;
            const float4* gp = (const float4*)&Wf[(col0 + m0) * DMODEL + ck * 32 + k8 * 8];
            float4 v0 = gp[0], v1 = gp[1];
            r[t] = make_uint4(pack2(v0.x, v0.y), pack2(v0.z, v0.w),
                              pack2(v1.x, v1.y), pack2(v1.z, v1.w));
        }
    };

    loadA(0, ra); loadB(0, rb);
    for (int ck = 0; ck < 16; ++ck) {
        __syncthreads();
        As8[k80 * 128 + m0] = ra[0]; As8[k81 * 128 + m0] = ra[1];
        Bs8[k80 * 128 + m0] = rb[0]; Bs8[k81 * 128 + m0] = rb[1];
        __syncthreads();
        if (ck < 15) { loadA(ck + 1, ra); loadB(ck + 1, rb); }
        const bf16x8* Av = (const bf16x8*)As8;
        const bf16x8* Bv = (const bf16x8*)Bs8;
        bf16x8 af[4], bfr[4];
        #pragma unroll
        for (int i = 0; i < 4; ++i) af[i]  = Av[quad * 128 + wm * 64 + i * 16 + l15];
        #pragma unroll
        for (int j = 0; j < 4; ++j) bfr[j] = Bv[quad * 128 + wn * 64 + j * 16 + l15];
        #pragma unroll
        for (int i = 0; i < 4; ++i)
            #pragma unroll
            for (int j = 0; j < 4; ++j)
                acc[i][j] = __builtin_amdgcn_mfma_f32_16x16x32_bf16(af[i], bfr[j], acc[i][j], 0, 0, 0);
    }
    #pragma unroll
    for (int i = 0; i < 4; ++i)
        #pragma unroll
        for (int j = 0; j < 4; ++j) {
            int c = col0 + wn * 64 + j * 16 + l15;
            float bv_ = bias[c];
            #pragma unroll
            for (int reg = 0; reg < 4; ++reg) {
                int r = row0 + wm * 64 + i * 16 + quad * 4 + reg;
                float v = acc[i][j][reg] + bv_;
                if (C_BF16) ((ushort_t*)Cp)[r * DMODEL + c] = f2bf(v);
                else        ((float*)Cp)[r * DMODEL + c] = v;
            }
        }
}

__global__ __launch_bounds__(256) void qkv_mfma_kernel(
    const float* __restrict__ xq, const float* __restrict__ xk, const float* __restrict__ xv,
    const float* __restrict__ Wq, const float* __restrict__ bq,
    const float* __restrict__ Wk, const float* __restrict__ bk,
    const float* __restrict__ Wv, const float* __restrict__ bv,
    ushort_t* __restrict__ Qb, ushort_t* __restrict__ Kb, ushort_t* __restrict__ Vb,
    unsigned int* __restrict__ minb)
{
    if (blockIdx.x == 0 && blockIdx.y == 0 && blockIdx.z == 0 && threadIdx.x == 0)
        *minb = 0x7f7fffffu;
    const float* X; const float* W; const float* bias; ushort_t* C;
    if (blockIdx.z == 0)      { X = xq; W = Wq; bias = bq; C = Qb; }
    else if (blockIdx.z == 1) { X = xk; W = Wk; bias = bk; C = Kb; }
    else                      { X = xv; W = Wv; bias = bv; C = Vb; }
    gemm_bt_mfma<false, true>(X, W, bias, C);
}

__global__ __launch_bounds__(256) void out_gemm_kernel(
    const ushort_t* __restrict__ ctxb, const float* __restrict__ Wo,
    const float* __restrict__ bo, float* __restrict__ out)
{
    gemm_bt_mfma<true, false>(ctxb, Wo, bo, out);
}

// ---------------- per-row sumsq of K + global min ---------------------------
__global__ __launch_bounds__(256) void rowss_kernel(
    const ushort_t* __restrict__ Kb, float* __restrict__ sumsq,
    unsigned int* __restrict__ minb)
{
    const int wave = threadIdx.x >> 6;
    const int lane = threadIdx.x & 63;
    const int l = blockIdx.x * 4 + wave;
    float mn = 3.4e38f;
    #pragma unroll
    for (int h = 0; h < NH; ++h) {
        float x = bf2f(Kb[l * DMODEL + h * DH + lane]);
        float ss = x * x;
        #pragma unroll
        for (int off = 32; off >= 1; off >>= 1) ss += __shfl_xor(ss, off, 64);
        if (lane == 0) sumsq[h * L + l] = ss;
        mn = fminf(mn, ss);
    }
    if (lane == 0) atomicMin(minb, __float_as_uint(mn));
}

// ---------------- q' / k' feature maps (bf16 in/out) ------------------------
__global__ __launch_bounds__(128) void primes_kernel(
    const ushort_t* __restrict__ Qb, const ushort_t* __restrict__ Kb,
    const float* __restrict__ RF, const float* __restrict__ sumsq,
    const unsigned int* __restrict__ minb,
    ushort_t* __restrict__ QPb, ushort_t* __restrict__ KPb)
{
    __shared__ float RFs[DH * M];
    __shared__ float qs[DH], ks[DH];
    const int tid = threadIdx.x;             // m index
    const int h  = blockIdx.y;
    const int l0 = blockIdx.x * 16;
    for (int i = tid * 4; i < DH * M; i += 512)
        *(float4*)&RFs[i] = *(const float4*)&RF[i];
    const float s2 = SCALE * SCALE;
    const float kst = -0.5f * s2 * __uint_as_float(*minb);   // global k stabilizer
    for (int li = 0; li < 16; ++li) {
        const int l = l0 + li;
        __syncthreads();
        if (tid < 64)  qs[tid]      = SCALE * bf2f(Qb[l * DMODEL + h * DH + tid]);
        else           ks[tid - 64] = SCALE * bf2f(Kb[l * DMODEL + h * DH + (tid - 64)]);
        __syncthreads();
        float pq = 0.f, pk = 0.f;
        #pragma unroll 8
        for (int d = 0; d < DH; ++d) {
            float rf = RFs[d * M + tid];
            pq += qs[d] * rf;
            pk += ks[d] * rf;
        }
        const float hk = -0.5f * s2 * sumsq[h * L + l];
        const int base = (h * L + l) * M + tid;
        QPb[base] = f2bf(NCONST * (expf(pq) + KEPS));        // q_stab == h_q cancels
        KPb[base] = f2bf(NCONST * (expf(hk - kst + pk) + KEPS));
    }
}

// ---------------- chunk sums: S_c^T = (K'^T V)^T stored [d][m], z_c ---------
__global__ __launch_bounds__(256) void chunksum_kernel(
    const ushort_t* __restrict__ KPb, const ushort_t* __restrict__ Vb,
    float* __restrict__ SS)
{
    __shared__ float kp[16][M];
    __shared__ float vs[16][DH];
    const int tid = threadIdx.x;
    const int c = blockIdx.x, h = blockIdx.y;
    const int m  = tid & 127;
    const int dg = tid >> 7;                  // 0..1 -> d block of 32
    float4 acc[8];
    #pragma unroll
    for (int g = 0; g < 8; ++g) acc[g] = make_float4(0.f, 0.f, 0.f, 0.f);
    float zacc = 0.f;
    for (int t0 = 0; t0 < CT; t0 += 16) {
        {   // kp: 16 rows x 128 bf16 = 256 uint4 tasks
            int r = tid >> 4, c8 = tid & 15;
            uint4 u = *(const uint4*)&KPb[((h * L) + c * CT + t0 + r) * M + c8 * 8];
            unpack8(u, &kp[r][c8 * 8]);
        }
        if (tid < 128) {  // vs: 16 rows x 64 bf16 = 128 uint4 tasks
            int r = tid >> 3, s = tid & 7;
            uint4 u = *(const uint4*)&Vb[(c * CT + t0 + r) * DMODEL + h * DH + s * 8];
            unpack8(u, &vs[r][s * 8]);
        }
        __syncthreads();
        #pragma unroll
        for (int ll = 0; ll < 16; ++ll) {
            float kv = kp[ll][m];
            if (dg == 0) zacc += kv;
            const float4* vp = (const float4*)&vs[ll][dg * 32];
            #pragma unroll
            for (int g = 0; g < 8; ++g) {
                float4 v4 = vp[g];
                acc[g].x += kv * v4.x; acc[g].y += kv * v4.y;
                acc[g].z += kv * v4.z; acc[g].w += kv * v4.w;
            }
        }
        __syncthreads();
    }
    float* out = SS + (h * NC + c) * 8320;
    #pragma unroll
    for (int g = 0; g < 8; ++g) {
        int d = dg * 32 + g * 4;
        out[(d+0) * M + m] = acc[g].x;
        out[(d+1) * M + m] = acc[g].y;
        out[(d+2) * M + m] = acc[g].z;
        out[(d+3) * M + m] = acc[g].w;
    }
    if (dg == 0) out[8192 + m] = zacc;
}

// ---------------- in-place exclusive prefix over chunks ---------------------
__global__ __launch_bounds__(256) void prefix_kernel(float* __restrict__ S)
{
    const int h = blockIdx.y;
    const int idx = blockIdx.x * 256 + threadIdx.x;
    if (idx >= 8320) return;
    float run = 0.f;
    for (int c = 0; c < NC; ++c) {
        float* p = S + (h * NC + c) * 8320 + idx;
        float v = *p;
        *p = run;
        run += v;
    }
}

// ---------------- per-chunk causal kernel attention (MFMA) ------------------
// Per block (c,h), 512 threads = 8 waves: wave = (i rows-tile, nh cols-half).
// Phase1: A = Q'K'^T (MFMA), mask, rowsum->den, Am->LDS bf16.
// Phase2: qz->den; N = [Am|Q'] @ [V;S^T] (MFMA, K=192); divide; write bf16 ctx.
__global__ __launch_bounds__(512) void attn_kernel(
    const ushort_t* __restrict__ QPb, const ushort_t* __restrict__ KPb,
    const ushort_t* __restrict__ Vb, const float* __restrict__ SP,
    ushort_t* __restrict__ ctxb)
{
    __shared__ ushort_t Qp[64 * 136];   // stride 136 bf16: 272B = 68 dw = 4 mod 32
    __shared__ ushort_t Kp[64 * 136];
    __shared__ ushort_t St[64 * 136];   // S^T: [d][m]
    __shared__ ushort_t Vt[64 * 72];    // V^T: [d][t]
    __shared__ ushort_t Am[64 * 72];    // masked scores [row][col]
    __shared__ float zl[M];
    __shared__ float den[CT];
    const int tid = threadIdx.x;
    const int c = blockIdx.x, h = blockIdx.y;
    const int lane = tid & 63;
    const int wave = tid >> 6;
    const int i  = wave & 3;            // rows tile (16 rows)
    const int nh = wave >> 2;           // cols half (32 cols)
    const int quad = lane >> 4;
    const int l15  = lane & 15;
    const long ssbase = (long)(h * NC + c) * 8320;

    // ---- stage ----
    for (int t = tid; t < 2048; t += 512) {          // Qp/Kp: 2 x 64 x 16 uint4
        int mat = t >> 10, r = (t >> 4) & 63, c8 = t & 15;
        const ushort_t* src = mat ? KPb : QPb;
        uint4 u = *(const uint4*)&src[((h * L) + c * CT + r) * M + c8 * 8];
        ushort_t* dst = mat ? Kp : Qp;
        *(uint4*)&dst[r * 136 + c8 * 8] = u;
    }
    {   // Vt: transpose V 64x64 bf16
        int t = tid & 63, dg = tid >> 6;             // dg 0..7 -> 8 d's
        uint4 u = *(const uint4*)&Vb[(c * CT + t) * DMODEL + h * DH + dg * 8];
        ushort_t e[8] = {(ushort_t)(u.x & 0xffff), (ushort_t)(u.x >> 16),
                         (ushort_t)(u.y & 0xffff), (ushort_t)(u.y >> 16),
                         (ushort_t)(u.z & 0xffff), (ushort_t)(u.z >> 16),
                         (ushort_t)(u.w & 0xffff), (ushort_t)(u.w >> 16)};
        #pragma unroll
        for (int j = 0; j < 8; ++j) Vt[(dg * 8 + j) * 72 + t] = e[j];
    }
    {   // St: 64 x 128 fp32 -> bf16
        int d = tid >> 3, s = tid & 7;
        const float4* gp = (const float4*)&SP[ssbase + d * M + s * 16];
        float4 f0 = gp[0], f1 = gp[1], f2 = gp[2], f3 = gp[3];
        uint4 u0 = make_uint4(pack2(f0.x, f0.y), pack2(f0.z, f0.w),
                              pack2(f1.x, f1.y), pack2(f1.z, f1.w));
        uint4 u1 = make_uint4(pack2(f2.x, f2.y), pack2(f2.z, f2.w),
                              pack2(f3.x, f3.y), pack2(f3.z, f3.w));
        *(uint4*)&St[d * 136 + s * 16] = u0;
        *(uint4*)&St[d * 136 + s * 16 + 8] = u1;
    }
    if (tid < M) zl[tid] = SP[ssbase + 8192 + tid];
    if (tid < CT) den[tid] = DEPS;
    __syncthreads();

    // ---- phase 1: scores ----
    f32x4 acc1[2];
    const f32x4 z4 = {0.f, 0.f, 0.f, 0.f};
    acc1[0] = z4; acc1[1] = z4;
    #pragma unroll
    for (int kt = 0; kt < 4; ++kt) {
        bf16x8 af = *(const bf16x8*)&Qp[(i * 16 + l15) * 136 + kt * 32 + quad * 8];
        #pragma unroll
        for (int jt = 0; jt < 2; ++jt) {
            bf16x8 bf = *(const bf16x8*)&Kp[(nh * 32 + jt * 16 + l15) * 136 + kt * 32 + quad * 8];
            acc1[jt] = __builtin_amdgcn_mfma_f32_16x16x32_bf16(af, bf, acc1[jt], 0, 0, 0);
        }
    }
    float rs[4] = {0.f, 0.f, 0.f, 0.f};
    #pragma unroll
    for (int jt = 0; jt < 2; ++jt) {
        int col = nh * 32 + jt * 16 + l15;
        #pragma unroll
        for (int reg = 0; reg < 4; ++reg) {
            int row = i * 16 + quad * 4 + reg;
            float v = (col <= row) ? acc1[jt][reg] : 0.f;
            Am[row * 72 + col] = f2bf(v);
            rs[reg] += v;
        }
    }
    #pragma unroll
    for (int reg = 0; reg < 4; ++reg) {
        #pragma unroll
        for (int off = 1; off < 16; off <<= 1) rs[reg] += __shfl_xor(rs[reg], off, 64);
    }
    if (l15 == 0) {
        #pragma unroll
        for (int reg = 0; reg < 4; ++reg)
            atomicAdd(&den[i * 16 + quad * 4 + reg], rs[reg]);
    }
    __syncthreads();

    // ---- phase 2: qz + N ----
    {
        int row = i * 16 + l15;
        int mb = nh * 64 + quad * 16;
        float qz = 0.f;
        #pragma unroll
        for (int mm = 0; mm < 16; ++mm)
            qz += bf2f(Qp[row * 136 + mb + mm]) * zl[mb + mm];
        qz += __shfl_xor(qz, 16, 64);
        qz += __shfl_xor(qz, 32, 64);
        if (quad == 0) atomicAdd(&den[row], qz);
    }
    f32x4 acc2[2];
    acc2[0] = z4; acc2[1] = z4;
    #pragma unroll
    for (int kt = 0; kt < 6; ++kt) {
        bf16x8 af = (kt < 2)
            ? *(const bf16x8*)&Am[(i * 16 + l15) * 72 + kt * 32 + quad * 8]
            : *(const bf16x8*)&Qp[(i * 16 + l15) * 136 + (kt - 2) * 32 + quad * 8];
        #pragma unroll
        for (int jt = 0; jt < 2; ++jt) {
            int n = nh * 32 + jt * 16 + l15;
            bf16x8 bf = (kt < 2)
                ? *(const bf16x8*)&Vt[n * 72 + kt * 32 + quad * 8]
                : *(const bf16x8*)&St[n * 136 + (kt - 2) * 32 + quad * 8];
            acc2[jt] = __builtin_amdgcn_mfma_f32_16x16x32_bf16(af, bf, acc2[jt], 0, 0, 0);
        }
    }
    __syncthreads();
    #pragma unroll
    for (int jt = 0; jt < 2; ++jt) {
        int d = nh * 32 + jt * 16 + l15;
        #pragma unroll
        for (int reg = 0; reg < 4; ++reg) {
            int row = i * 16 + quad * 4 + reg;
            ctxb[(c * CT + row) * DMODEL + h * DH + d] = f2bf(acc2[jt][reg] / den[row]);
        }
    }
}

extern "C" void kernel_launch(void* const* d_in, const int* in_sizes, int n_in,
                              void* d_out, int out_size, void* d_ws, size_t ws_size,
                              hipStream_t stream)
{
    const float* query = (const float*)d_in[0];
    const float* key_  = (const float*)d_in[1];
    const float* value = (const float*)d_in[2];
    const float* Wq = (const float*)d_in[3];
    const float* bq = (const float*)d_in[4];
    const float* Wk = (const float*)d_in[5];
    const float* bk = (const float*)d_in[6];
    const float* Wv = (const float*)d_in[7];
    const float* bv = (const float*)d_in[8];
    const float* Wo = (const float*)d_in[9];
    const float* bo = (const float*)d_in[10];
    const float* RF = (const float*)d_in[11];

    float* ws = (float*)d_ws;
    ushort_t* Qb  = (ushort_t*)(ws + OFF_QB);
    ushort_t* Kb  = (ushort_t*)(ws + OFF_KB);
    ushort_t* Vb  = (ushort_t*)(ws + OFF_VB);
    ushort_t* QPb = (ushort_t*)(ws + OFF_QPB);
    ushort_t* KPb = (ushort_t*)(ws + OFF_KPB);
    float* SS     = ws + OFF_SS;
    ushort_t* CTXB = (ushort_t*)(ws + OFF_CTX);
    float* SUMSQ  = ws + OFF_SUMSQ;
    unsigned int* MINB = (unsigned int*)(ws + OFF_MINB);

    qkv_mfma_kernel<<<dim3(16, 4, 3), 256, 0, stream>>>(query, key_, value,
                                                        Wq, bq, Wk, bk, Wv, bv,
                                                        Qb, Kb, Vb, MINB);
    rowss_kernel<<<512, 256, 0, stream>>>(Kb, SUMSQ, MINB);
    primes_kernel<<<dim3(128, 8), 128, 0, stream>>>(Qb, Kb, RF, SUMSQ, MINB, QPb, KPb);
    chunksum_kernel<<<dim3(NC, 8), 256, 0, stream>>>(KPb, Vb, SS);
    prefix_kernel<<<dim3(33, 8), 256, 0, stream>>>(SS);
    attn_kernel<<<dim3(NC, 8), 512, 0, stream>>>(QPb, KPb, Vb, SS, CTXB);
    out_gemm_kernel<<<dim3(16, 4), 256, 0, stream>>>(CTXB, Wo, bo, (float*)d_out);
}

// Round 5
// 193.475 us; speedup vs baseline: 1.5802x; 1.1305x over previous
//
#include <hip/hip_runtime.h>
#include <math.h>

// Performer (FAVOR+) causal attention. B=1, L=2048, D=512, H=8, DH=64, M=128.
// Round 5: identical to round 4 (primes->MFMA, bf16 S^T) but with FIXED
// workspace offsets — round 4 halved the bf16 extents, overlapping Qb/Kb/Vb.

#define L       2048
#define DMODEL  512
#define NH      8
#define DH      64
#define M       128
#define CT      64          // chunk size
#define NC      (L/CT)      // 32 chunks per head
#define KEPS    1e-4f
#define DEPS    1e-6f
#define SCALE   0.2102241038134286f   // 512^-0.25
#define NCONST  0.08838834764831845f  // 128^-0.5

// workspace layout (float offsets). total = 5296129 floats = 21.2 MB
// sizes: Qb/Kb/Vb = 2048*512 bf16 = 524288 floats EACH; QPb/KPb = 8*2048*128
// bf16 = 1048576 floats EACH; SSb = 8*32*8192 bf16 = 1048576; SSz = 32768;
// CTX = 524288; SUMSQ = 16384; RFT = 8192 bf16 = 4096.
#define OFF_QB     0          // bf16 [l][512]
#define OFF_KB     524288
#define OFF_VB     1048576
#define OFF_QPB    1572864    // bf16 [h][l][m]
#define OFF_KPB    2621440
#define OFF_SSB    3670016    // bf16 [h][c][d*128+m]  (S^T), prefix in-place
#define OFF_SSZ    4718592    // fp32 [h][c][m]        (z),   prefix in-place
#define OFF_CTX    4751360    // bf16 [l][512]
#define OFF_SUMSQ  5275648    // fp32 [h][l]
#define OFF_RFT    5292032    // bf16 [m][d], SCALE folded
#define OFF_MINB   5296128    // 1 uint

typedef short bf16x8 __attribute__((ext_vector_type(8)));
typedef float f32x4  __attribute__((ext_vector_type(4)));
typedef unsigned short ushort_t;

__device__ __forceinline__ ushort_t f2bf(float f) {
    unsigned u = __float_as_uint(f);
    return (ushort_t)((u + 0x7fffu + ((u >> 16) & 1u)) >> 16);
}
__device__ __forceinline__ float bf2f(ushort_t u) {
    return __uint_as_float(((unsigned)u) << 16);
}
__device__ __forceinline__ unsigned pack2(float a, float b) {
    return (unsigned)f2bf(a) | ((unsigned)f2bf(b) << 16);
}
__device__ __forceinline__ void unpack8(uint4 u, float* d) {
    d[0] = bf2f(u.x & 0xffff); d[1] = bf2f(u.x >> 16);
    d[2] = bf2f(u.y & 0xffff); d[3] = bf2f(u.y >> 16);
    d[4] = bf2f(u.z & 0xffff); d[5] = bf2f(u.z >> 16);
    d[6] = bf2f(u.w & 0xffff); d[7] = bf2f(u.w >> 16);
}

// ---------------- bf16 MFMA GEMM: C = A @ W^T + bias (K=512) ----------------
template<bool A_BF16, bool C_BF16>
__device__ __forceinline__ void gemm_bt_mfma(const void* __restrict__ Ap,
                                             const float* __restrict__ Wf,
                                             const float* __restrict__ bias,
                                             void* __restrict__ Cp)
{
    __shared__ uint4 As8[512];   // 8 KB: A tile 128x32 bf16, [k8][m]
    __shared__ uint4 Bs8[512];
    const int tid  = threadIdx.x;
    const int lane = tid & 63;
    const int wave = tid >> 6;
    const int wm = wave >> 1, wn = wave & 1;
    const int row0 = blockIdx.x * 128;
    const int col0 = blockIdx.y * 128;
    const int quad = lane >> 4;
    const int l15  = lane & 15;
    const int m0  = tid & 127;
    const int k80 = tid >> 7;
    const int k81 = k80 + 2;

    f32x4 acc[4][4];
    const f32x4 z4 = {0.f, 0.f, 0.f, 0.f};
    #pragma unroll
    for (int i = 0; i < 4; ++i)
        #pragma unroll
        for (int j = 0; j < 4; ++j) acc[i][j] = z4;

    uint4 ra[2], rb[2];
    auto loadA = [&](int ck, uint4* r) {
        if (A_BF16) {
            const uint4* Ag = (const uint4*)Ap;
            r[0] = Ag[(row0 + m0) * (DMODEL / 8) + ck * 4 + k80];
            r[1] = Ag[(row0 + m0) * (DMODEL / 8) + ck * 4 + k81];
        } else {
            const float* Af = (const float*)Ap;
            #pragma unroll
            for (int t = 0; t < 2; ++t) {
                int k8 = t ? k81 : k80;
                const float4* gp = (const float4*)&Af[(row0 + m0) * DMODEL + ck * 32 + k8 * 8];
                float4 v0 = gp[0], v1 = gp[1];
                r[t] = make_uint4(pack2(v0.x, v0.y), pack2(v0.z, v0.w),
                                  pack2(v1.x, v1.y), pack2(v1.z, v1.w));
            }
        }
    };
    auto loadB = [&](int ck, uint4* r) {
        #pragma unroll
        for (int t = 0; t < 2; ++t) {
            int k8 = t ? k81 : k80;
            const float4* gp = (const float4*)&Wf[(col0 + m0) * DMODEL + ck * 32 + k8 * 8];
            float4 v0 = gp[0], v1 = gp[1];
            r[t] = make_uint4(pack2(v0.x, v0.y), pack2(v0.z, v0.w),
                              pack2(v1.x, v1.y), pack2(v1.z, v1.w));
        }
    };

    loadA(0, ra); loadB(0, rb);
    for (int ck = 0; ck < 16; ++ck) {
        __syncthreads();
        As8[k80 * 128 + m0] = ra[0]; As8[k81 * 128 + m0] = ra[1];
        Bs8[k80 * 128 + m0] = rb[0]; Bs8[k81 * 128 + m0] = rb[1];
        __syncthreads();
        if (ck < 15) { loadA(ck + 1, ra); loadB(ck + 1, rb); }
        const bf16x8* Av = (const bf16x8*)As8;
        const bf16x8* Bv = (const bf16x8*)Bs8;
        bf16x8 af[4], bfr[4];
        #pragma unroll
        for (int i = 0; i < 4; ++i) af[i]  = Av[quad * 128 + wm * 64 + i * 16 + l15];
        #pragma unroll
        for (int j = 0; j < 4; ++j) bfr[j] = Bv[quad * 128 + wn * 64 + j * 16 + l15];
        #pragma unroll
        for (int i = 0; i < 4; ++i)
            #pragma unroll
            for (int j = 0; j < 4; ++j)
                acc[i][j] = __builtin_amdgcn_mfma_f32_16x16x32_bf16(af[i], bfr[j], acc[i][j], 0, 0, 0);
    }
    #pragma unroll
    for (int i = 0; i < 4; ++i)
        #pragma unroll
        for (int j = 0; j < 4; ++j) {
            int c = col0 + wn * 64 + j * 16 + l15;
            float bv_ = bias[c];
            #pragma unroll
            for (int reg = 0; reg < 4; ++reg) {
                int r = row0 + wm * 64 + i * 16 + quad * 4 + reg;
                float v = acc[i][j][reg] + bv_;
                if (C_BF16) ((ushort_t*)Cp)[r * DMODEL + c] = f2bf(v);
                else        ((float*)Cp)[r * DMODEL + c] = v;
            }
        }
}

__global__ __launch_bounds__(256) void qkv_mfma_kernel(
    const float* __restrict__ xq, const float* __restrict__ xk, const float* __restrict__ xv,
    const float* __restrict__ Wq, const float* __restrict__ bq,
    const float* __restrict__ Wk, const float* __restrict__ bk,
    const float* __restrict__ Wv, const float* __restrict__ bv,
    ushort_t* __restrict__ Qb, ushort_t* __restrict__ Kb, ushort_t* __restrict__ Vb,
    unsigned int* __restrict__ minb)
{
    if (blockIdx.x == 0 && blockIdx.y == 0 && blockIdx.z == 0 && threadIdx.x == 0)
        *minb = 0x7f7fffffu;
    const float* X; const float* W; const float* bias; ushort_t* C;
    if (blockIdx.z == 0)      { X = xq; W = Wq; bias = bq; C = Qb; }
    else if (blockIdx.z == 1) { X = xk; W = Wk; bias = bk; C = Kb; }
    else                      { X = xv; W = Wv; bias = bv; C = Vb; }
    gemm_bt_mfma<false, true>(X, W, bias, C);
}

__global__ __launch_bounds__(256) void out_gemm_kernel(
    const ushort_t* __restrict__ ctxb, const float* __restrict__ Wo,
    const float* __restrict__ bo, float* __restrict__ out)
{
    gemm_bt_mfma<true, false>(ctxb, Wo, bo, out);
}

// ------- per-row sumsq of K + global min; block 512 preps RF^T bf16 ---------
__global__ __launch_bounds__(256) void rowss_kernel(
    const ushort_t* __restrict__ Kb, const float* __restrict__ RF,
    float* __restrict__ sumsq, unsigned int* __restrict__ minb,
    ushort_t* __restrict__ RFT)
{
    const int tid = threadIdx.x;
    if (blockIdx.x == 512) {
        // RFT[m][d] = bf16(SCALE * RF[d][m])
        __shared__ float rf[DH * M];
        for (int t = tid; t < DH * M; t += 256) rf[t] = RF[t];
        __syncthreads();
        for (int t = tid; t < 1024; t += 256) {
            int m = t >> 3, k8 = t & 7;
            float v[8];
            #pragma unroll
            for (int j = 0; j < 8; ++j) v[j] = SCALE * rf[(k8 * 8 + j) * M + m];
            uint4 u = make_uint4(pack2(v[0], v[1]), pack2(v[2], v[3]),
                                 pack2(v[4], v[5]), pack2(v[6], v[7]));
            *(uint4*)&RFT[m * DH + k8 * 8] = u;
        }
        return;
    }
    const int wave = tid >> 6;
    const int lane = tid & 63;
    const int l = blockIdx.x * 4 + wave;
    float mn = 3.4e38f;
    #pragma unroll
    for (int h = 0; h < NH; ++h) {
        float x = bf2f(Kb[l * DMODEL + h * DH + lane]);
        float ss = x * x;
        #pragma unroll
        for (int off = 32; off >= 1; off >>= 1) ss += __shfl_xor(ss, off, 64);
        if (lane == 0) sumsq[h * L + l] = ss;
        mn = fminf(mn, ss);
    }
    if (lane == 0) atomicMin(minb, __float_as_uint(mn));
}

// ---------------- q'/k' feature maps via MFMA -------------------------------
// block: 128 l-rows x 128 m-cols, K=64. blockIdx: (l-tile, h, isK).
__global__ __launch_bounds__(256) void primes_mfma_kernel(
    const ushort_t* __restrict__ Qb, const ushort_t* __restrict__ Kb,
    const ushort_t* __restrict__ RFT, const float* __restrict__ sumsq,
    const unsigned int* __restrict__ minb,
    ushort_t* __restrict__ QPb, ushort_t* __restrict__ KPb)
{
    __shared__ uint4 As8[8 * 128];   // [k8][row] 16 KB
    __shared__ uint4 Bs8[8 * 128];   // [k8][m]
    __shared__ float ssq[128];
    const int tid  = threadIdx.x;
    const int lane = tid & 63;
    const int wave = tid >> 6;
    const int wm = wave >> 1, wn = wave & 1;
    const int quad = lane >> 4;
    const int l15  = lane & 15;
    const int h   = blockIdx.y;
    const int isK = blockIdx.z;
    const int l0  = blockIdx.x * 128;
    const ushort_t* src = isK ? Kb : Qb;

    #pragma unroll
    for (int it = 0; it < 4; ++it) {
        int t = tid + it * 256;
        int k8 = t >> 7, m0 = t & 127;
        As8[k8 * 128 + m0] = *(const uint4*)&src[(l0 + m0) * DMODEL + h * DH + k8 * 8];
        Bs8[k8 * 128 + m0] = *(const uint4*)&RFT[m0 * DH + k8 * 8];
    }
    if (isK && tid < 128) ssq[tid] = sumsq[h * L + l0 + tid];
    const float minv = __uint_as_float(*minb);
    const float s2h = 0.5f * SCALE * SCALE;
    __syncthreads();

    f32x4 acc[4][4];
    const f32x4 z4 = {0.f, 0.f, 0.f, 0.f};
    #pragma unroll
    for (int i = 0; i < 4; ++i)
        #pragma unroll
        for (int j = 0; j < 4; ++j) acc[i][j] = z4;
    const bf16x8* Av = (const bf16x8*)As8;
    const bf16x8* Bv = (const bf16x8*)Bs8;
    #pragma unroll
    for (int kk = 0; kk < 2; ++kk) {
        const int k8 = kk * 4 + quad;
        bf16x8 af[4], bfr[4];
        #pragma unroll
        for (int i = 0; i < 4; ++i) af[i]  = Av[k8 * 128 + wm * 64 + i * 16 + l15];
        #pragma unroll
        for (int j = 0; j < 4; ++j) bfr[j] = Bv[k8 * 128 + wn * 64 + j * 16 + l15];
        #pragma unroll
        for (int i = 0; i < 4; ++i)
            #pragma unroll
            for (int j = 0; j < 4; ++j)
                acc[i][j] = __builtin_amdgcn_mfma_f32_16x16x32_bf16(af[i], bfr[j], acc[i][j], 0, 0, 0);
    }

    ushort_t* dst = isK ? KPb : QPb;
    #pragma unroll
    for (int i = 0; i < 4; ++i)
        #pragma unroll
        for (int reg = 0; reg < 4; ++reg) {
            int row = wm * 64 + i * 16 + quad * 4 + reg;
            float off = isK ? (-s2h * (ssq[row] - minv)) : 0.f;
            #pragma unroll
            for (int j = 0; j < 4; ++j) {
                int col = wn * 64 + j * 16 + l15;
                float p = acc[i][j][reg] + off;
                dst[(h * L + l0 + row) * M + col] = f2bf(NCONST * (expf(p) + KEPS));
            }
        }
}

// ---------------- chunk sums: S_c^T bf16 [d][m], z_c fp32 -------------------
__global__ __launch_bounds__(256) void chunksum_kernel(
    const ushort_t* __restrict__ KPb, const ushort_t* __restrict__ Vb,
    ushort_t* __restrict__ SSb, float* __restrict__ SSz)
{
    __shared__ float kp[16][M];
    __shared__ float vs[16][DH];
    const int tid = threadIdx.x;
    const int c = blockIdx.x, h = blockIdx.y;
    const int m  = tid & 127;
    const int dg = tid >> 7;                  // 0..1 -> d block of 32
    float4 acc[8];
    #pragma unroll
    for (int g = 0; g < 8; ++g) acc[g] = make_float4(0.f, 0.f, 0.f, 0.f);
    float zacc = 0.f;
    for (int t0 = 0; t0 < CT; t0 += 16) {
        {   int r = tid >> 4, c8 = tid & 15;
            uint4 u = *(const uint4*)&KPb[((h * L) + c * CT + t0 + r) * M + c8 * 8];
            unpack8(u, &kp[r][c8 * 8]);
        }
        if (tid < 128) {
            int r = tid >> 3, s = tid & 7;
            uint4 u = *(const uint4*)&Vb[(c * CT + t0 + r) * DMODEL + h * DH + s * 8];
            unpack8(u, &vs[r][s * 8]);
        }
        __syncthreads();
        #pragma unroll
        for (int ll = 0; ll < 16; ++ll) {
            float kv = kp[ll][m];
            if (dg == 0) zacc += kv;
            const float4* vp = (const float4*)&vs[ll][dg * 32];
            #pragma unroll
            for (int g = 0; g < 8; ++g) {
                float4 v4 = vp[g];
                acc[g].x += kv * v4.x; acc[g].y += kv * v4.y;
                acc[g].z += kv * v4.z; acc[g].w += kv * v4.w;
            }
        }
        __syncthreads();
    }
    ushort_t* outb = SSb + (h * NC + c) * 8192;
    #pragma unroll
    for (int g = 0; g < 8; ++g) {
        int d = dg * 32 + g * 4;
        outb[(d+0) * M + m] = f2bf(acc[g].x);
        outb[(d+1) * M + m] = f2bf(acc[g].y);
        outb[(d+2) * M + m] = f2bf(acc[g].z);
        outb[(d+3) * M + m] = f2bf(acc[g].w);
    }
    if (dg == 0) SSz[(h * NC + c) * M + m] = zacc;
}

// ---------------- in-place exclusive prefix over chunks ---------------------
__global__ __launch_bounds__(256) void prefix_kernel(
    ushort_t* __restrict__ SSb, float* __restrict__ SSz)
{
    const int h = blockIdx.y;
    if (blockIdx.x == 32) {
        const int m = threadIdx.x;
        if (m < M) {
            float run = 0.f;
            for (int c = 0; c < NC; ++c) {
                float* p = &SSz[(h * NC + c) * M + m];
                float v = *p; *p = run; run += v;
            }
        }
        return;
    }
    const int idx = blockIdx.x * 256 + threadIdx.x;   // < 8192
    float run = 0.f;
    for (int c = 0; c < NC; ++c) {
        ushort_t* p = &SSb[(h * NC + c) * 8192 + idx];
        float v = bf2f(*p); *p = f2bf(run); run += v;
    }
}

// ---------------- per-chunk causal kernel attention (MFMA) ------------------
__global__ __launch_bounds__(512) void attn_kernel(
    const ushort_t* __restrict__ QPb, const ushort_t* __restrict__ KPb,
    const ushort_t* __restrict__ Vb, const ushort_t* __restrict__ SSb,
    const float* __restrict__ SSz, ushort_t* __restrict__ ctxb)
{
    __shared__ ushort_t Qp[64 * 136];   // stride 136 bf16
    __shared__ ushort_t Kp[64 * 136];
    __shared__ ushort_t St[64 * 136];   // S^T: [d][m]
    __shared__ ushort_t Vt[64 * 72];    // V^T: [d][t]
    __shared__ ushort_t Am[64 * 72];    // masked scores [row][col]
    __shared__ float zl[M];
    __shared__ float den[CT];
    const int tid = threadIdx.x;
    const int c = blockIdx.x, h = blockIdx.y;
    const int lane = tid & 63;
    const int wave = tid >> 6;
    const int i  = wave & 3;            // rows tile (16 rows)
    const int nh = wave >> 2;           // cols half (32 cols)
    const int quad = lane >> 4;
    const int l15  = lane & 15;

    // ---- stage ----
    for (int t = tid; t < 2048; t += 512) {          // Qp/Kp
        int mat = t >> 10, r = (t >> 4) & 63, c8 = t & 15;
        const ushort_t* src = mat ? KPb : QPb;
        uint4 u = *(const uint4*)&src[((h * L) + c * CT + r) * M + c8 * 8];
        ushort_t* dst = mat ? Kp : Qp;
        *(uint4*)&dst[r * 136 + c8 * 8] = u;
    }
    {   // Vt: transpose V 64x64 bf16
        int t = tid & 63, dg = tid >> 6;
        uint4 u = *(const uint4*)&Vb[(c * CT + t) * DMODEL + h * DH + dg * 8];
        ushort_t e[8] = {(ushort_t)(u.x & 0xffff), (ushort_t)(u.x >> 16),
                         (ushort_t)(u.y & 0xffff), (ushort_t)(u.y >> 16),
                         (ushort_t)(u.z & 0xffff), (ushort_t)(u.z >> 16),
                         (ushort_t)(u.w & 0xffff), (ushort_t)(u.w >> 16)};
        #pragma unroll
        for (int j = 0; j < 8; ++j) Vt[(dg * 8 + j) * 72 + t] = e[j];
    }
    {   // St: straight bf16 copy
        const ushort_t* ssb = SSb + (long)(h * NC + c) * 8192;
        for (int t = tid; t < 1024; t += 512) {
            int d = t >> 4, c8 = t & 15;
            *(uint4*)&St[d * 136 + c8 * 8] = *(const uint4*)&ssb[d * 128 + c8 * 8];
        }
    }
    if (tid < M) zl[tid] = SSz[(h * NC + c) * M + tid];
    if (tid < CT) den[tid] = DEPS;
    __syncthreads();

    // ---- phase 1: scores ----
    f32x4 acc1[2];
    const f32x4 z4 = {0.f, 0.f, 0.f, 0.f};
    acc1[0] = z4; acc1[1] = z4;
    #pragma unroll
    for (int kt = 0; kt < 4; ++kt) {
        bf16x8 af = *(const bf16x8*)&Qp[(i * 16 + l15) * 136 + kt * 32 + quad * 8];
        #pragma unroll
        for (int jt = 0; jt < 2; ++jt) {
            bf16x8 bf = *(const bf16x8*)&Kp[(nh * 32 + jt * 16 + l15) * 136 + kt * 32 + quad * 8];
            acc1[jt] = __builtin_amdgcn_mfma_f32_16x16x32_bf16(af, bf, acc1[jt], 0, 0, 0);
        }
    }
    float rs[4] = {0.f, 0.f, 0.f, 0.f};
    #pragma unroll
    for (int jt = 0; jt < 2; ++jt) {
        int col = nh * 32 + jt * 16 + l15;
        #pragma unroll
        for (int reg = 0; reg < 4; ++reg) {
            int row = i * 16 + quad * 4 + reg;
            float v = (col <= row) ? acc1[jt][reg] : 0.f;
            Am[row * 72 + col] = f2bf(v);
            rs[reg] += v;
        }
    }
    #pragma unroll
    for (int reg = 0; reg < 4; ++reg) {
        #pragma unroll
        for (int off = 1; off < 16; off <<= 1) rs[reg] += __shfl_xor(rs[reg], off, 64);
    }
    if (l15 == 0) {
        #pragma unroll
        for (int reg = 0; reg < 4; ++reg)
            atomicAdd(&den[i * 16 + quad * 4 + reg], rs[reg]);
    }
    __syncthreads();

    // ---- phase 2: qz + N ----
    {
        int row = i * 16 + l15;
        int mb = nh * 64 + quad * 16;
        float qz = 0.f;
        #pragma unroll
        for (int mm = 0; mm < 16; ++mm)
            qz += bf2f(Qp[row * 136 + mb + mm]) * zl[mb + mm];
        qz += __shfl_xor(qz, 16, 64);
        qz += __shfl_xor(qz, 32, 64);
        if (quad == 0) atomicAdd(&den[row], qz);
    }
    f32x4 acc2[2];
    acc2[0] = z4; acc2[1] = z4;
    #pragma unroll
    for (int kt = 0; kt < 6; ++kt) {
        bf16x8 af = (kt < 2)
            ? *(const bf16x8*)&Am[(i * 16 + l15) * 72 + kt * 32 + quad * 8]
            : *(const bf16x8*)&Qp[(i * 16 + l15) * 136 + (kt - 2) * 32 + quad * 8];
        #pragma unroll
        for (int jt = 0; jt < 2; ++jt) {
            int n = nh * 32 + jt * 16 + l15;
            bf16x8 bf = (kt < 2)
                ? *(const bf16x8*)&Vt[n * 72 + kt * 32 + quad * 8]
                : *(const bf16x8*)&St[n * 136 + (kt - 2) * 32 + quad * 8];
            acc2[jt] = __builtin_amdgcn_mfma_f32_16x16x32_bf16(af, bf, acc2[jt], 0, 0, 0);
        }
    }
    __syncthreads();
    #pragma unroll
    for (int jt = 0; jt < 2; ++jt) {
        int d = nh * 32 + jt * 16 + l15;
        #pragma unroll
        for (int reg = 0; reg < 4; ++reg) {
            int row = i * 16 + quad * 4 + reg;
            ctxb[(c * CT + row) * DMODEL + h * DH + d] = f2bf(acc2[jt][reg] / den[row]);
        }
    }
}

extern "C" void kernel_launch(void* const* d_in, const int* in_sizes, int n_in,
                              void* d_out, int out_size, void* d_ws, size_t ws_size,
                              hipStream_t stream)
{
    const float* query = (const float*)d_in[0];
    const float* key_  = (const float*)d_in[1];
    const float* value = (const float*)d_in[2];
    const float* Wq = (const float*)d_in[3];
    const float* bq = (const float*)d_in[4];
    const float* Wk = (const float*)d_in[5];
    const float* bk = (const float*)d_in[6];
    const float* Wv = (const float*)d_in[7];
    const float* bv = (const float*)d_in[8];
    const float* Wo = (const float*)d_in[9];
    const float* bo = (const float*)d_in[10];
    const float* RF = (const float*)d_in[11];

    float* ws = (float*)d_ws;
    ushort_t* Qb  = (ushort_t*)(ws + OFF_QB);
    ushort_t* Kb  = (ushort_t*)(ws + OFF_KB);
    ushort_t* Vb  = (ushort_t*)(ws + OFF_VB);
    ushort_t* QPb = (ushort_t*)(ws + OFF_QPB);
    ushort_t* KPb = (ushort_t*)(ws + OFF_KPB);
    ushort_t* SSb = (ushort_t*)(ws + OFF_SSB);
    float* SSz    = ws + OFF_SSZ;
    ushort_t* CTXB = (ushort_t*)(ws + OFF_CTX);
    float* SUMSQ  = ws + OFF_SUMSQ;
    ushort_t* RFT = (ushort_t*)(ws + OFF_RFT);
    unsigned int* MINB = (unsigned int*)(ws + OFF_MINB);

    qkv_mfma_kernel<<<dim3(16, 4, 3), 256, 0, stream>>>(query, key_, value,
                                                        Wq, bq, Wk, bk, Wv, bv,
                                                        Qb, Kb, Vb, MINB);
    rowss_kernel<<<513, 256, 0, stream>>>(Kb, RF, SUMSQ, MINB, RFT);
    primes_mfma_kernel<<<dim3(16, 8, 2), 256, 0, stream>>>(Qb, Kb, RFT, SUMSQ, MINB, QPb, KPb);
    chunksum_kernel<<<dim3(NC, 8), 256, 0, stream>>>(KPb, Vb, SSb, SSz);
    prefix_kernel<<<dim3(33, 8), 256, 0, stream>>>(SSb, SSz);
    attn_kernel<<<dim3(NC, 8), 512, 0, stream>>>(QPb, KPb, Vb, SSb, SSz, CTXB);
    out_gemm_kernel<<<dim3(16, 4), 256, 0, stream>>>(CTXB, Wo, bo, (float*)d_out);
}

// Round 6
// 176.789 us; speedup vs baseline: 1.7294x; 1.0944x over previous
//
#include <hip/hip_runtime.h>
#include <math.h>

// Performer (FAVOR+) causal attention. B=1, L=2048, D=512, H=8, DH=64, M=128.
// Round 6: GEMM row-tile templated (qkv 64x128 -> 384 blocks, out 32x128 ->
// 256 blocks); chunksum -> MFMA (S = K'^T V via LDS transposes, z via
// ones-row trick); SSb now stores S [m][d]; attn St staging transposes.

#define L       2048
#define DMODEL  512
#define NH      8
#define DH      64
#define M       128
#define CT      64          // chunk size
#define NC      (L/CT)      // 32 chunks per head
#define KEPS    1e-4f
#define DEPS    1e-6f
#define SCALE   0.2102241038134286f   // 512^-0.25
#define NCONST  0.08838834764831845f  // 128^-0.5

// workspace layout (float offsets). total = 5296129 floats = 21.2 MB
#define OFF_QB     0          // bf16 [l][512]
#define OFF_KB     524288
#define OFF_VB     1048576
#define OFF_QPB    1572864    // bf16 [h][l][m]
#define OFF_KPB    2621440
#define OFF_SSB    3670016    // bf16 [h][c][m*64+d]  (S), prefix in-place
#define OFF_SSZ    4718592    // fp32 [h][c][m]       (z), prefix in-place
#define OFF_CTX    4751360    // bf16 [l][512]
#define OFF_SUMSQ  5275648    // fp32 [h][l]
#define OFF_RFT    5292032    // bf16 [m][d], SCALE folded
#define OFF_MINB   5296128    // 1 uint

typedef short bf16x8 __attribute__((ext_vector_type(8)));
typedef float f32x4  __attribute__((ext_vector_type(4)));
typedef unsigned short ushort_t;

__device__ __forceinline__ ushort_t f2bf(float f) {
    unsigned u = __float_as_uint(f);
    return (ushort_t)((u + 0x7fffu + ((u >> 16) & 1u)) >> 16);
}
__device__ __forceinline__ float bf2f(ushort_t u) {
    return __uint_as_float(((unsigned)u) << 16);
}
__device__ __forceinline__ unsigned pack2(float a, float b) {
    return (unsigned)f2bf(a) | ((unsigned)f2bf(b) << 16);
}

// ------- bf16 MFMA GEMM: C = A @ W^T + bias, tile (NRT*16) x 128, K=512 -----
// 256 threads = 4 waves; wave w owns col-quarter w*32, all rows.
template<int NRT, bool A_BF16, bool C_BF16>
__device__ __forceinline__ void gemm_bt_mfma(const void* __restrict__ Ap,
                                             const float* __restrict__ Wf,
                                             const float* __restrict__ bias,
                                             void* __restrict__ Cp)
{
    constexpr int NROWS = NRT * 16;
    __shared__ uint4 As8[4 * NROWS];   // [k8][row] bf16x8
    __shared__ uint4 Bs8[4 * 128];     // [k8][col]
    const int tid  = threadIdx.x;
    const int lane = tid & 63;
    const int wn   = tid >> 6;         // wave -> col quarter
    const int row0 = blockIdx.x * NROWS;
    const int col0 = blockIdx.y * 128;
    const int quad = lane >> 4;
    const int l15  = lane & 15;

    f32x4 acc[NRT][2];
    const f32x4 z4 = {0.f, 0.f, 0.f, 0.f};
    #pragma unroll
    for (int i = 0; i < NRT; ++i)
        #pragma unroll
        for (int j = 0; j < 2; ++j) acc[i][j] = z4;

    uint4 ra[1], rb[2];
    auto loadA = [&](int ck) {
        int idx = 0;
        for (int t = tid; t < 4 * NROWS; t += 256, ++idx) {
            int k8 = t / NROWS, row = t % NROWS;
            if (A_BF16) {
                ra[idx] = *(const uint4*)&((const ushort_t*)Ap)[(row0 + row) * DMODEL + ck * 32 + k8 * 8];
            } else {
                const float4* gp = (const float4*)&((const float*)Ap)[(row0 + row) * DMODEL + ck * 32 + k8 * 8];
                float4 v0 = gp[0], v1 = gp[1];
                ra[idx] = make_uint4(pack2(v0.x, v0.y), pack2(v0.z, v0.w),
                                     pack2(v1.x, v1.y), pack2(v1.z, v1.w));
            }
        }
    };
    auto loadB = [&](int ck) {
        #pragma unroll
        for (int it = 0; it < 2; ++it) {
            int t = tid + it * 256;
            int k8 = t >> 7, col = t & 127;
            const float4* gp = (const float4*)&Wf[(col0 + col) * DMODEL + ck * 32 + k8 * 8];
            float4 v0 = gp[0], v1 = gp[1];
            rb[it] = make_uint4(pack2(v0.x, v0.y), pack2(v0.z, v0.w),
                                pack2(v1.x, v1.y), pack2(v1.z, v1.w));
        }
    };

    loadA(0); loadB(0);
    for (int ck = 0; ck < 16; ++ck) {
        __syncthreads();
        {   int idx = 0;
            for (int t = tid; t < 4 * NROWS; t += 256, ++idx) As8[t] = ra[idx];
            Bs8[tid] = rb[0]; Bs8[tid + 256] = rb[1];
        }
        __syncthreads();
        if (ck < 15) { loadA(ck + 1); loadB(ck + 1); }
        const bf16x8* Av = (const bf16x8*)As8;
        const bf16x8* Bv = (const bf16x8*)Bs8;
        bf16x8 af[NRT], bfr[2];
        #pragma unroll
        for (int i = 0; i < NRT; ++i) af[i] = Av[quad * NROWS + i * 16 + l15];
        #pragma unroll
        for (int j = 0; j < 2; ++j)   bfr[j] = Bv[quad * 128 + wn * 32 + j * 16 + l15];
        #pragma unroll
        for (int i = 0; i < NRT; ++i)
            #pragma unroll
            for (int j = 0; j < 2; ++j)
                acc[i][j] = __builtin_amdgcn_mfma_f32_16x16x32_bf16(af[i], bfr[j], acc[i][j], 0, 0, 0);
    }
    #pragma unroll
    for (int i = 0; i < NRT; ++i)
        #pragma unroll
        for (int j = 0; j < 2; ++j) {
            int c = col0 + wn * 32 + j * 16 + l15;
            float bv_ = bias[c];
            #pragma unroll
            for (int reg = 0; reg < 4; ++reg) {
                int r = row0 + i * 16 + quad * 4 + reg;
                float v = acc[i][j][reg] + bv_;
                if (C_BF16) ((ushort_t*)Cp)[r * DMODEL + c] = f2bf(v);
                else        ((float*)Cp)[r * DMODEL + c] = v;
            }
        }
}

__global__ __launch_bounds__(256) void qkv_mfma_kernel(
    const float* __restrict__ xq, const float* __restrict__ xk, const float* __restrict__ xv,
    const float* __restrict__ Wq, const float* __restrict__ bq,
    const float* __restrict__ Wk, const float* __restrict__ bk,
    const float* __restrict__ Wv, const float* __restrict__ bv,
    ushort_t* __restrict__ Qb, ushort_t* __restrict__ Kb, ushort_t* __restrict__ Vb,
    unsigned int* __restrict__ minb)
{
    if (blockIdx.x == 0 && blockIdx.y == 0 && blockIdx.z == 0 && threadIdx.x == 0)
        *minb = 0x7f7fffffu;
    const float* X; const float* W; const float* bias; ushort_t* C;
    if (blockIdx.z == 0)      { X = xq; W = Wq; bias = bq; C = Qb; }
    else if (blockIdx.z == 1) { X = xk; W = Wk; bias = bk; C = Kb; }
    else                      { X = xv; W = Wv; bias = bv; C = Vb; }
    gemm_bt_mfma<4, false, true>(X, W, bias, C);
}

__global__ __launch_bounds__(256) void out_gemm_kernel(
    const ushort_t* __restrict__ ctxb, const float* __restrict__ Wo,
    const float* __restrict__ bo, float* __restrict__ out)
{
    gemm_bt_mfma<2, true, false>(ctxb, Wo, bo, out);
}

// ------- per-row sumsq of K + global min; block 512 preps RF^T bf16 ---------
__global__ __launch_bounds__(256) void rowss_kernel(
    const ushort_t* __restrict__ Kb, const float* __restrict__ RF,
    float* __restrict__ sumsq, unsigned int* __restrict__ minb,
    ushort_t* __restrict__ RFT)
{
    const int tid = threadIdx.x;
    if (blockIdx.x == 512) {
        __shared__ float rf[DH * M];
        for (int t = tid; t < DH * M; t += 256) rf[t] = RF[t];
        __syncthreads();
        for (int t = tid; t < 1024; t += 256) {
            int m = t >> 3, k8 = t & 7;
            float v[8];
            #pragma unroll
            for (int j = 0; j < 8; ++j) v[j] = SCALE * rf[(k8 * 8 + j) * M + m];
            uint4 u = make_uint4(pack2(v[0], v[1]), pack2(v[2], v[3]),
                                 pack2(v[4], v[5]), pack2(v[6], v[7]));
            *(uint4*)&RFT[m * DH + k8 * 8] = u;
        }
        return;
    }
    const int wave = tid >> 6;
    const int lane = tid & 63;
    const int l = blockIdx.x * 4 + wave;
    float mn = 3.4e38f;
    #pragma unroll
    for (int h = 0; h < NH; ++h) {
        float x = bf2f(Kb[l * DMODEL + h * DH + lane]);
        float ss = x * x;
        #pragma unroll
        for (int off = 32; off >= 1; off >>= 1) ss += __shfl_xor(ss, off, 64);
        if (lane == 0) sumsq[h * L + l] = ss;
        mn = fminf(mn, ss);
    }
    if (lane == 0) atomicMin(minb, __float_as_uint(mn));
}

// ---------------- q'/k' feature maps via MFMA -------------------------------
__global__ __launch_bounds__(256) void primes_mfma_kernel(
    const ushort_t* __restrict__ Qb, const ushort_t* __restrict__ Kb,
    const ushort_t* __restrict__ RFT, const float* __restrict__ sumsq,
    const unsigned int* __restrict__ minb,
    ushort_t* __restrict__ QPb, ushort_t* __restrict__ KPb)
{
    __shared__ uint4 As8[8 * 128];   // [k8][row]
    __shared__ uint4 Bs8[8 * 128];   // [k8][m]
    __shared__ float ssq[128];
    const int tid  = threadIdx.x;
    const int lane = tid & 63;
    const int wave = tid >> 6;
    const int wm = wave >> 1, wn = wave & 1;
    const int quad = lane >> 4;
    const int l15  = lane & 15;
    const int h   = blockIdx.y;
    const int isK = blockIdx.z;
    const int l0  = blockIdx.x * 128;
    const ushort_t* src = isK ? Kb : Qb;

    #pragma unroll
    for (int it = 0; it < 4; ++it) {
        int t = tid + it * 256;
        int k8 = t >> 7, m0 = t & 127;
        As8[k8 * 128 + m0] = *(const uint4*)&src[(l0 + m0) * DMODEL + h * DH + k8 * 8];
        Bs8[k8 * 128 + m0] = *(const uint4*)&RFT[m0 * DH + k8 * 8];
    }
    if (isK && tid < 128) ssq[tid] = sumsq[h * L + l0 + tid];
    const float minv = __uint_as_float(*minb);
    const float s2h = 0.5f * SCALE * SCALE;
    __syncthreads();

    f32x4 acc[4][4];
    const f32x4 z4 = {0.f, 0.f, 0.f, 0.f};
    #pragma unroll
    for (int i = 0; i < 4; ++i)
        #pragma unroll
        for (int j = 0; j < 4; ++j) acc[i][j] = z4;
    const bf16x8* Av = (const bf16x8*)As8;
    const bf16x8* Bv = (const bf16x8*)Bs8;
    #pragma unroll
    for (int kk = 0; kk < 2; ++kk) {
        const int k8 = kk * 4 + quad;
        bf16x8 af[4], bfr[4];
        #pragma unroll
        for (int i = 0; i < 4; ++i) af[i]  = Av[k8 * 128 + wm * 64 + i * 16 + l15];
        #pragma unroll
        for (int j = 0; j < 4; ++j) bfr[j] = Bv[k8 * 128 + wn * 64 + j * 16 + l15];
        #pragma unroll
        for (int i = 0; i < 4; ++i)
            #pragma unroll
            for (int j = 0; j < 4; ++j)
                acc[i][j] = __builtin_amdgcn_mfma_f32_16x16x32_bf16(af[i], bfr[j], acc[i][j], 0, 0, 0);
    }

    ushort_t* dst = isK ? KPb : QPb;
    #pragma unroll
    for (int i = 0; i < 4; ++i)
        #pragma unroll
        for (int reg = 0; reg < 4; ++reg) {
            int row = wm * 64 + i * 16 + quad * 4 + reg;
            float off = isK ? (-s2h * (ssq[row] - minv)) : 0.f;
            #pragma unroll
            for (int j = 0; j < 4; ++j) {
                int col = wn * 64 + j * 16 + l15;
                float p = acc[i][j][reg] + off;
                dst[(h * L + l0 + row) * M + col] = f2bf(NCONST * (expf(p) + KEPS));
            }
        }
}

// ------- chunk sums via MFMA: S[m][d] = K'^T V, z[m] via ones-row -----------
__global__ __launch_bounds__(256) void chunksum_mfma_kernel(
    const ushort_t* __restrict__ KPb, const ushort_t* __restrict__ Vb,
    ushort_t* __restrict__ SSb, float* __restrict__ SSz)
{
    __shared__ ushort_t Kt[128 * 72];   // K'^T [m][t]
    __shared__ ushort_t Vt[80 * 72];    // V^T [d][t]; row 64 = ones; 65..79 zero
    const int tid = threadIdx.x;
    const int c = blockIdx.x, h = blockIdx.y;
    const int lane = tid & 63;
    const int wave = tid >> 6;
    const int quad = lane >> 4, l15 = lane & 15;
    const int t = lane, g = wave;

    {   // transpose-stage K' (64x128) and V (64x64); lanes along t -> conflict-free
        const ushort_t* kr = &KPb[((h * L) + c * CT + t) * M];
        #pragma unroll
        for (int it = 0; it < 4; ++it) {
            int mo = it * 4 + g;
            uint4 u = *(const uint4*)&kr[mo * 8];
            ushort_t e[8] = {(ushort_t)(u.x & 0xffff), (ushort_t)(u.x >> 16),
                             (ushort_t)(u.y & 0xffff), (ushort_t)(u.y >> 16),
                             (ushort_t)(u.z & 0xffff), (ushort_t)(u.z >> 16),
                             (ushort_t)(u.w & 0xffff), (ushort_t)(u.w >> 16)};
            #pragma unroll
            for (int j = 0; j < 8; ++j) Kt[(mo * 8 + j) * 72 + t] = e[j];
        }
        const ushort_t* vr = &Vb[(c * CT + t) * DMODEL + h * DH];
        #pragma unroll
        for (int it = 0; it < 2; ++it) {
            int dd = it * 4 + g;
            uint4 u = *(const uint4*)&vr[dd * 8];
            ushort_t e[8] = {(ushort_t)(u.x & 0xffff), (ushort_t)(u.x >> 16),
                             (ushort_t)(u.y & 0xffff), (ushort_t)(u.y >> 16),
                             (ushort_t)(u.z & 0xffff), (ushort_t)(u.z >> 16),
                             (ushort_t)(u.w & 0xffff), (ushort_t)(u.w >> 16)};
            #pragma unroll
            for (int j = 0; j < 8; ++j) Vt[(dd * 8 + j) * 72 + t] = e[j];
        }
        if (g == 0) Vt[64 * 72 + t] = 0x3F80;     // bf16 1.0
        if (g == 1) {
            #pragma unroll
            for (int r = 65; r < 80; ++r) Vt[r * 72 + t] = 0;
        }
    }
    __syncthreads();

    f32x4 acc[2][5];
    const f32x4 z4 = {0.f, 0.f, 0.f, 0.f};
    #pragma unroll
    for (int i = 0; i < 2; ++i)
        #pragma unroll
        for (int j = 0; j < 5; ++j) acc[i][j] = z4;
    #pragma unroll
    for (int kt = 0; kt < 2; ++kt) {
        bf16x8 af[2], bfr[5];
        #pragma unroll
        for (int i = 0; i < 2; ++i)
            af[i] = *(const bf16x8*)&Kt[(wave * 32 + i * 16 + l15) * 72 + kt * 32 + quad * 8];
        #pragma unroll
        for (int j = 0; j < 5; ++j)
            bfr[j] = *(const bf16x8*)&Vt[(j * 16 + l15) * 72 + kt * 32 + quad * 8];
        #pragma unroll
        for (int i = 0; i < 2; ++i)
            #pragma unroll
            for (int j = 0; j < 5; ++j)
                acc[i][j] = __builtin_amdgcn_mfma_f32_16x16x32_bf16(af[i], bfr[j], acc[i][j], 0, 0, 0);
    }
    ushort_t* outS = SSb + (h * NC + c) * 8192;
    #pragma unroll
    for (int i = 0; i < 2; ++i)
        #pragma unroll
        for (int reg = 0; reg < 4; ++reg) {
            int m = wave * 32 + i * 16 + quad * 4 + reg;
            #pragma unroll
            for (int j = 0; j < 4; ++j)
                outS[m * 64 + j * 16 + l15] = f2bf(acc[i][j][reg]);
            if (l15 == 0) SSz[(h * NC + c) * M + m] = acc[i][4][reg];
        }
}

// ---------------- in-place exclusive prefix over chunks ---------------------
__global__ __launch_bounds__(256) void prefix_kernel(
    ushort_t* __restrict__ SSb, float* __restrict__ SSz)
{
    const int h = blockIdx.y;
    if (blockIdx.x == 32) {
        const int m = threadIdx.x;
        if (m < M) {
            float run = 0.f;
            for (int c = 0; c < NC; ++c) {
                float* p = &SSz[(h * NC + c) * M + m];
                float v = *p; *p = run; run += v;
            }
        }
        return;
    }
    const int idx = blockIdx.x * 256 + threadIdx.x;   // < 8192
    float run = 0.f;
    for (int c = 0; c < NC; ++c) {
        ushort_t* p = &SSb[(h * NC + c) * 8192 + idx];
        float v = bf2f(*p); *p = f2bf(run); run += v;
    }
}

// ---------------- per-chunk causal kernel attention (MFMA) ------------------
__global__ __launch_bounds__(512) void attn_kernel(
    const ushort_t* __restrict__ QPb, const ushort_t* __restrict__ KPb,
    const ushort_t* __restrict__ Vb, const ushort_t* __restrict__ SSb,
    const float* __restrict__ SSz, ushort_t* __restrict__ ctxb)
{
    __shared__ ushort_t Qp[64 * 136];   // stride 136 bf16
    __shared__ ushort_t Kp[64 * 136];
    __shared__ ushort_t St[64 * 136];   // S^T: [d][m]
    __shared__ ushort_t Vt[64 * 72];    // V^T: [d][t]
    __shared__ ushort_t Am[64 * 72];    // masked scores [row][col]
    __shared__ float zl[M];
    __shared__ float den[CT];
    const int tid = threadIdx.x;
    const int c = blockIdx.x, h = blockIdx.y;
    const int lane = tid & 63;
    const int wave = tid >> 6;
    const int i  = wave & 3;            // rows tile (16 rows)
    const int nh = wave >> 2;           // cols half (32 cols)
    const int quad = lane >> 4;
    const int l15  = lane & 15;

    // ---- stage ----
    for (int t = tid; t < 2048; t += 512) {          // Qp/Kp
        int mat = t >> 10, r = (t >> 4) & 63, c8 = t & 15;
        const ushort_t* src = mat ? KPb : QPb;
        uint4 u = *(const uint4*)&src[((h * L) + c * CT + r) * M + c8 * 8];
        ushort_t* dst = mat ? Kp : Qp;
        *(uint4*)&dst[r * 136 + c8 * 8] = u;
    }
    {   // Vt: transpose V 64x64 bf16
        int t = tid & 63, dg = tid >> 6;
        uint4 u = *(const uint4*)&Vb[(c * CT + t) * DMODEL + h * DH + dg * 8];
        ushort_t e[8] = {(ushort_t)(u.x & 0xffff), (ushort_t)(u.x >> 16),
                         (ushort_t)(u.y & 0xffff), (ushort_t)(u.y >> 16),
                         (ushort_t)(u.z & 0xffff), (ushort_t)(u.z >> 16),
                         (ushort_t)(u.w & 0xffff), (ushort_t)(u.w >> 16)};
        #pragma unroll
        for (int j = 0; j < 8; ++j) Vt[(dg * 8 + j) * 72 + t] = e[j];
    }
    {   // St[d][m] from S[m][d] (transpose-scatter, lanes along m -> free)
        const ushort_t* ssb = SSb + (long)(h * NC + c) * 8192;
        int m = tid & 127, dg = tid >> 7;    // dg 0..3
        #pragma unroll
        for (int it = 0; it < 2; ++it) {
            int dd = it * 4 + dg;            // d-octet 0..7
            uint4 u = *(const uint4*)&ssb[m * 64 + dd * 8];
            ushort_t e[8] = {(ushort_t)(u.x & 0xffff), (ushort_t)(u.x >> 16),
                             (ushort_t)(u.y & 0xffff), (ushort_t)(u.y >> 16),
                             (ushort_t)(u.z & 0xffff), (ushort_t)(u.z >> 16),
                             (ushort_t)(u.w & 0xffff), (ushort_t)(u.w >> 16)};
            #pragma unroll
            for (int j = 0; j < 8; ++j) St[(dd * 8 + j) * 136 + m] = e[j];
        }
    }
    if (tid < M) zl[tid] = SSz[(h * NC + c) * M + tid];
    if (tid < CT) den[tid] = DEPS;
    __syncthreads();

    // ---- phase 1: scores ----
    f32x4 acc1[2];
    const f32x4 z4 = {0.f, 0.f, 0.f, 0.f};
    acc1[0] = z4; acc1[1] = z4;
    #pragma unroll
    for (int kt = 0; kt < 4; ++kt) {
        bf16x8 af = *(const bf16x8*)&Qp[(i * 16 + l15) * 136 + kt * 32 + quad * 8];
        #pragma unroll
        for (int jt = 0; jt < 2; ++jt) {
            bf16x8 bf = *(const bf16x8*)&Kp[(nh * 32 + jt * 16 + l15) * 136 + kt * 32 + quad * 8];
            acc1[jt] = __builtin_amdgcn_mfma_f32_16x16x32_bf16(af, bf, acc1[jt], 0, 0, 0);
        }
    }
    float rs[4] = {0.f, 0.f, 0.f, 0.f};
    #pragma unroll
    for (int jt = 0; jt < 2; ++jt) {
        int col = nh * 32 + jt * 16 + l15;
        #pragma unroll
        for (int reg = 0; reg < 4; ++reg) {
            int row = i * 16 + quad * 4 + reg;
            float v = (col <= row) ? acc1[jt][reg] : 0.f;
            Am[row * 72 + col] = f2bf(v);
            rs[reg] += v;
        }
    }
    #pragma unroll
    for (int reg = 0; reg < 4; ++reg) {
        #pragma unroll
        for (int off = 1; off < 16; off <<= 1) rs[reg] += __shfl_xor(rs[reg], off, 64);
    }
    if (l15 == 0) {
        #pragma unroll
        for (int reg = 0; reg < 4; ++reg)
            atomicAdd(&den[i * 16 + quad * 4 + reg], rs[reg]);
    }
    __syncthreads();

    // ---- phase 2: qz + N ----
    {
        int row = i * 16 + l15;
        int mb = nh * 64 + quad * 16;
        float qz = 0.f;
        #pragma unroll
        for (int mm = 0; mm < 16; ++mm)
            qz += bf2f(Qp[row * 136 + mb + mm]) * zl[mb + mm];
        qz += __shfl_xor(qz, 16, 64);
        qz += __shfl_xor(qz, 32, 64);
        if (quad == 0) atomicAdd(&den[row], qz);
    }
    f32x4 acc2[2];
    acc2[0] = z4; acc2[1] = z4;
    #pragma unroll
    for (int kt = 0; kt < 6; ++kt) {
        bf16x8 af = (kt < 2)
            ? *(const bf16x8*)&Am[(i * 16 + l15) * 72 + kt * 32 + quad * 8]
            : *(const bf16x8*)&Qp[(i * 16 + l15) * 136 + (kt - 2) * 32 + quad * 8];
        #pragma unroll
        for (int jt = 0; jt < 2; ++jt) {
            int n = nh * 32 + jt * 16 + l15;
            bf16x8 bf = (kt < 2)
                ? *(const bf16x8*)&Vt[n * 72 + kt * 32 + quad * 8]
                : *(const bf16x8*)&St[n * 136 + (kt - 2) * 32 + quad * 8];
            acc2[jt] = __builtin_amdgcn_mfma_f32_16x16x32_bf16(af, bf, acc2[jt], 0, 0, 0);
        }
    }
    __syncthreads();
    #pragma unroll
    for (int jt = 0; jt < 2; ++jt) {
        int d = nh * 32 + jt * 16 + l15;
        #pragma unroll
        for (int reg = 0; reg < 4; ++reg) {
            int row = i * 16 + quad * 4 + reg;
            ctxb[(c * CT + row) * DMODEL + h * DH + d] = f2bf(acc2[jt][reg] / den[row]);
        }
    }
}

extern "C" void kernel_launch(void* const* d_in, const int* in_sizes, int n_in,
                              void* d_out, int out_size, void* d_ws, size_t ws_size,
                              hipStream_t stream)
{
    const float* query = (const float*)d_in[0];
    const float* key_  = (const float*)d_in[1];
    const float* value = (const float*)d_in[2];
    const float* Wq = (const float*)d_in[3];
    const float* bq = (const float*)d_in[4];
    const float* Wk = (const float*)d_in[5];
    const float* bk = (const float*)d_in[6];
    const float* Wv = (const float*)d_in[7];
    const float* bv = (const float*)d_in[8];
    const float* Wo = (const float*)d_in[9];
    const float* bo = (const float*)d_in[10];
    const float* RF = (const float*)d_in[11];

    float* ws = (float*)d_ws;
    ushort_t* Qb  = (ushort_t*)(ws + OFF_QB);
    ushort_t* Kb  = (ushort_t*)(ws + OFF_KB);
    ushort_t* Vb  = (ushort_t*)(ws + OFF_VB);
    ushort_t* QPb = (ushort_t*)(ws + OFF_QPB);
    ushort_t* KPb = (ushort_t*)(ws + OFF_KPB);
    ushort_t* SSb = (ushort_t*)(ws + OFF_SSB);
    float* SSz    = ws + OFF_SSZ;
    ushort_t* CTXB = (ushort_t*)(ws + OFF_CTX);
    float* SUMSQ  = ws + OFF_SUMSQ;
    ushort_t* RFT = (ushort_t*)(ws + OFF_RFT);
    unsigned int* MINB = (unsigned int*)(ws + OFF_MINB);

    qkv_mfma_kernel<<<dim3(32, 4, 3), 256, 0, stream>>>(query, key_, value,
                                                        Wq, bq, Wk, bk, Wv, bv,
                                                        Qb, Kb, Vb, MINB);
    rowss_kernel<<<513, 256, 0, stream>>>(Kb, RF, SUMSQ, MINB, RFT);
    primes_mfma_kernel<<<dim3(16, 8, 2), 256, 0, stream>>>(Qb, Kb, RFT, SUMSQ, MINB, QPb, KPb);
    chunksum_mfma_kernel<<<dim3(NC, 8), 256, 0, stream>>>(KPb, Vb, SSb, SSz);
    prefix_kernel<<<dim3(33, 8), 256, 0, stream>>>(SSb, SSz);
    attn_kernel<<<dim3(NC, 8), 512, 0, stream>>>(QPb, KPb, Vb, SSb, SSz, CTXB);
    out_gemm_kernel<<<dim3(64, 4), 256, 0, stream>>>(CTXB, Wo, bo, (float*)d_out);
}

// Round 7
// 149.878 us; speedup vs baseline: 2.0399x; 1.1795x over previous
//
#include <hip/hip_runtime.h>
#include <math.h>

// Performer (FAVOR+) causal attention. B=1, L=2048, D=512, H=8, DH=64, M=128.
// Round 7: rowss dropped (kst=0 is a common-scale no-op up to KEPS mixing;
// sumsq inline in primes; RFT prep folded into qkv z=3); prefix batch-load
// scan; attn den computed as MFMA output column 64 via ones/z rows.

#define L       2048
#define DMODEL  512
#define NH      8
#define DH      64
#define M       128
#define CT      64          // chunk size
#define NC      (L/CT)      // 32 chunks per head
#define KEPS    1e-4f
#define DEPS    1e-6f
#define SCALE   0.2102241038134286f   // 512^-0.25
#define NCONST  0.08838834764831845f  // 128^-0.5

// workspace layout (float offsets). total = 5296128 floats = 21.2 MB
#define OFF_QB     0          // bf16 [l][512]
#define OFF_KB     524288
#define OFF_VB     1048576
#define OFF_QPB    1572864    // bf16 [h][l][m]
#define OFF_KPB    2621440
#define OFF_SSB    3670016    // bf16 [h][c][m*64+d]  (S), prefix in-place
#define OFF_SSZ    4718592    // fp32 [h][c][m]       (z), prefix in-place
#define OFF_CTX    4751360    // bf16 [l][512]
#define OFF_RFT    5275648    // bf16 [m][d], SCALE folded
#define OFF_END    5279744

typedef short bf16x8 __attribute__((ext_vector_type(8)));
typedef float f32x4  __attribute__((ext_vector_type(4)));
typedef unsigned short ushort_t;

__device__ __forceinline__ ushort_t f2bf(float f) {
    unsigned u = __float_as_uint(f);
    return (ushort_t)((u + 0x7fffu + ((u >> 16) & 1u)) >> 16);
}
__device__ __forceinline__ float bf2f(ushort_t u) {
    return __uint_as_float(((unsigned)u) << 16);
}
__device__ __forceinline__ unsigned pack2(float a, float b) {
    return (unsigned)f2bf(a) | ((unsigned)f2bf(b) << 16);
}
__device__ __forceinline__ void unpack8(uint4 u, float* d) {
    d[0] = bf2f(u.x & 0xffff); d[1] = bf2f(u.x >> 16);
    d[2] = bf2f(u.y & 0xffff); d[3] = bf2f(u.y >> 16);
    d[4] = bf2f(u.z & 0xffff); d[5] = bf2f(u.z >> 16);
    d[6] = bf2f(u.w & 0xffff); d[7] = bf2f(u.w >> 16);
}

// ------- bf16 MFMA GEMM: C = A @ W^T + bias, tile (NRT*16) x 128, K=512 -----
template<int NRT, bool A_BF16, bool C_BF16>
__device__ __forceinline__ void gemm_bt_mfma(const void* __restrict__ Ap,
                                             const float* __restrict__ Wf,
                                             const float* __restrict__ bias,
                                             void* __restrict__ Cp)
{
    constexpr int NROWS = NRT * 16;
    __shared__ uint4 As8[4 * NROWS];   // [k8][row] bf16x8
    __shared__ uint4 Bs8[4 * 128];     // [k8][col]
    const int tid  = threadIdx.x;
    const int lane = tid & 63;
    const int wn   = tid >> 6;         // wave -> col quarter
    const int row0 = blockIdx.x * NROWS;
    const int col0 = blockIdx.y * 128;
    const int quad = lane >> 4;
    const int l15  = lane & 15;

    f32x4 acc[NRT][2];
    const f32x4 z4 = {0.f, 0.f, 0.f, 0.f};
    #pragma unroll
    for (int i = 0; i < NRT; ++i)
        #pragma unroll
        for (int j = 0; j < 2; ++j) acc[i][j] = z4;

    uint4 ra[1], rb[2];
    auto loadA = [&](int ck) {
        int idx = 0;
        for (int t = tid; t < 4 * NROWS; t += 256, ++idx) {
            int k8 = t / NROWS, row = t % NROWS;
            if (A_BF16) {
                ra[idx] = *(const uint4*)&((const ushort_t*)Ap)[(row0 + row) * DMODEL + ck * 32 + k8 * 8];
            } else {
                const float4* gp = (const float4*)&((const float*)Ap)[(row0 + row) * DMODEL + ck * 32 + k8 * 8];
                float4 v0 = gp[0], v1 = gp[1];
                ra[idx] = make_uint4(pack2(v0.x, v0.y), pack2(v0.z, v0.w),
                                     pack2(v1.x, v1.y), pack2(v1.z, v1.w));
            }
        }
    };
    auto loadB = [&](int ck) {
        #pragma unroll
        for (int it = 0; it < 2; ++it) {
            int t = tid + it * 256;
            int k8 = t >> 7, col = t & 127;
            const float4* gp = (const float4*)&Wf[(col0 + col) * DMODEL + ck * 32 + k8 * 8];
            float4 v0 = gp[0], v1 = gp[1];
            rb[it] = make_uint4(pack2(v0.x, v0.y), pack2(v0.z, v0.w),
                                pack2(v1.x, v1.y), pack2(v1.z, v1.w));
        }
    };

    loadA(0); loadB(0);
    for (int ck = 0; ck < 16; ++ck) {
        __syncthreads();
        {   int idx = 0;
            for (int t = tid; t < 4 * NROWS; t += 256, ++idx) As8[t] = ra[idx];
            Bs8[tid] = rb[0]; Bs8[tid + 256] = rb[1];
        }
        __syncthreads();
        if (ck < 15) { loadA(ck + 1); loadB(ck + 1); }
        const bf16x8* Av = (const bf16x8*)As8;
        const bf16x8* Bv = (const bf16x8*)Bs8;
        bf16x8 af[NRT], bfr[2];
        #pragma unroll
        for (int i = 0; i < NRT; ++i) af[i] = Av[quad * NROWS + i * 16 + l15];
        #pragma unroll
        for (int j = 0; j < 2; ++j)   bfr[j] = Bv[quad * 128 + wn * 32 + j * 16 + l15];
        #pragma unroll
        for (int i = 0; i < NRT; ++i)
            #pragma unroll
            for (int j = 0; j < 2; ++j)
                acc[i][j] = __builtin_amdgcn_mfma_f32_16x16x32_bf16(af[i], bfr[j], acc[i][j], 0, 0, 0);
    }
    #pragma unroll
    for (int i = 0; i < NRT; ++i)
        #pragma unroll
        for (int j = 0; j < 2; ++j) {
            int c = col0 + wn * 32 + j * 16 + l15;
            float bv_ = bias[c];
            #pragma unroll
            for (int reg = 0; reg < 4; ++reg) {
                int r = row0 + i * 16 + quad * 4 + reg;
                float v = acc[i][j][reg] + bv_;
                if (C_BF16) ((ushort_t*)Cp)[r * DMODEL + c] = f2bf(v);
                else        ((float*)Cp)[r * DMODEL + c] = v;
            }
        }
}

// z in {0,1,2}: Q/K/V projection GEMMs. z==3: one block preps RF^T bf16.
__global__ __launch_bounds__(256) void qkv_mfma_kernel(
    const float* __restrict__ xq, const float* __restrict__ xk, const float* __restrict__ xv,
    const float* __restrict__ Wq, const float* __restrict__ bq,
    const float* __restrict__ Wk, const float* __restrict__ bk,
    const float* __restrict__ Wv, const float* __restrict__ bv,
    const float* __restrict__ RF,
    ushort_t* __restrict__ Qb, ushort_t* __restrict__ Kb, ushort_t* __restrict__ Vb,
    ushort_t* __restrict__ RFT)
{
    if (blockIdx.z == 3) {
        if (blockIdx.x == 0 && blockIdx.y == 0) {
            // RFT[m][d] = bf16(SCALE * RF[d][m]); 256 thr x 32 elems
            int m = threadIdx.x >> 1, d0 = (threadIdx.x & 1) * 32;
            for (int j = 0; j < 32; ++j)
                RFT[m * DH + d0 + j] = f2bf(SCALE * RF[(d0 + j) * M + m]);
        }
        return;
    }
    const float* X; const float* W; const float* bias; ushort_t* C;
    if (blockIdx.z == 0)      { X = xq; W = Wq; bias = bq; C = Qb; }
    else if (blockIdx.z == 1) { X = xk; W = Wk; bias = bk; C = Kb; }
    else                      { X = xv; W = Wv; bias = bv; C = Vb; }
    gemm_bt_mfma<4, false, true>(X, W, bias, C);
}

__global__ __launch_bounds__(256) void out_gemm_kernel(
    const ushort_t* __restrict__ ctxb, const float* __restrict__ Wo,
    const float* __restrict__ bo, float* __restrict__ out)
{
    gemm_bt_mfma<2, true, false>(ctxb, Wo, bo, out);
}

// ---------------- q'/k' feature maps via MFMA (kst = 0, ssq inline) ---------
__global__ __launch_bounds__(256) void primes_mfma_kernel(
    const ushort_t* __restrict__ Qb, const ushort_t* __restrict__ Kb,
    const ushort_t* __restrict__ RFT,
    ushort_t* __restrict__ QPb, ushort_t* __restrict__ KPb)
{
    __shared__ uint4 As8[8 * 128];   // [k8][row]
    __shared__ uint4 Bs8[8 * 128];   // [k8][m]
    __shared__ float ssq[128];
    const int tid  = threadIdx.x;
    const int lane = tid & 63;
    const int wave = tid >> 6;
    const int wm = wave >> 1, wn = wave & 1;
    const int quad = lane >> 4;
    const int l15  = lane & 15;
    const int h   = blockIdx.y;
    const int isK = blockIdx.z;
    const int l0  = blockIdx.x * 128;
    const ushort_t* src = isK ? Kb : Qb;

    #pragma unroll
    for (int it = 0; it < 4; ++it) {
        int t = tid + it * 256;
        int k8 = t >> 7, m0 = t & 127;
        As8[k8 * 128 + m0] = *(const uint4*)&src[(l0 + m0) * DMODEL + h * DH + k8 * 8];
        Bs8[k8 * 128 + m0] = *(const uint4*)&RFT[m0 * DH + k8 * 8];
    }
    const float s2h = 0.5f * SCALE * SCALE;
    __syncthreads();

    if (isK && tid < 128) {        // per-row sumsq of the staged K rows
        float s = 0.f;
        #pragma unroll
        for (int k8 = 0; k8 < 8; ++k8) {
            float d[8];
            unpack8(As8[k8 * 128 + tid], d);
            #pragma unroll
            for (int j = 0; j < 8; ++j) s += d[j] * d[j];
        }
        ssq[tid] = s;
    }

    f32x4 acc[4][4];
    const f32x4 z4 = {0.f, 0.f, 0.f, 0.f};
    #pragma unroll
    for (int i = 0; i < 4; ++i)
        #pragma unroll
        for (int j = 0; j < 4; ++j) acc[i][j] = z4;
    const bf16x8* Av = (const bf16x8*)As8;
    const bf16x8* Bv = (const bf16x8*)Bs8;
    #pragma unroll
    for (int kk = 0; kk < 2; ++kk) {
        const int k8 = kk * 4 + quad;
        bf16x8 af[4], bfr[4];
        #pragma unroll
        for (int i = 0; i < 4; ++i) af[i]  = Av[k8 * 128 + wm * 64 + i * 16 + l15];
        #pragma unroll
        for (int j = 0; j < 4; ++j) bfr[j] = Bv[k8 * 128 + wn * 64 + j * 16 + l15];
        #pragma unroll
        for (int i = 0; i < 4; ++i)
            #pragma unroll
            for (int j = 0; j < 4; ++j)
                acc[i][j] = __builtin_amdgcn_mfma_f32_16x16x32_bf16(af[i], bfr[j], acc[i][j], 0, 0, 0);
    }
    __syncthreads();               // ssq visible to all waves

    ushort_t* dst = isK ? KPb : QPb;
    #pragma unroll
    for (int i = 0; i < 4; ++i)
        #pragma unroll
        for (int reg = 0; reg < 4; ++reg) {
            int row = wm * 64 + i * 16 + quad * 4 + reg;
            float off = isK ? (-s2h * ssq[row]) : 0.f;
            #pragma unroll
            for (int j = 0; j < 4; ++j) {
                int col = wn * 64 + j * 16 + l15;
                float p = acc[i][j][reg] + off;
                dst[(h * L + l0 + row) * M + col] = f2bf(NCONST * (expf(p) + KEPS));
            }
        }
}

// ------- chunk sums via MFMA: S[m][d] = K'^T V, z[m] via ones-row -----------
__global__ __launch_bounds__(256) void chunksum_mfma_kernel(
    const ushort_t* __restrict__ KPb, const ushort_t* __restrict__ Vb,
    ushort_t* __restrict__ SSb, float* __restrict__ SSz)
{
    __shared__ ushort_t Kt[128 * 72];   // K'^T [m][t]
    __shared__ ushort_t Vt[80 * 72];    // V^T [d][t]; row 64 = ones; 65..79 zero
    const int tid = threadIdx.x;
    const int c = blockIdx.x, h = blockIdx.y;
    const int lane = tid & 63;
    const int wave = tid >> 6;
    const int quad = lane >> 4, l15 = lane & 15;
    const int t = lane, g = wave;

    {   // transpose-stage K' (64x128) and V (64x64); lanes along t -> conflict-free
        const ushort_t* kr = &KPb[((h * L) + c * CT + t) * M];
        #pragma unroll
        for (int it = 0; it < 4; ++it) {
            int mo = it * 4 + g;
            uint4 u = *(const uint4*)&kr[mo * 8];
            ushort_t e[8] = {(ushort_t)(u.x & 0xffff), (ushort_t)(u.x >> 16),
                             (ushort_t)(u.y & 0xffff), (ushort_t)(u.y >> 16),
                             (ushort_t)(u.z & 0xffff), (ushort_t)(u.z >> 16),
                             (ushort_t)(u.w & 0xffff), (ushort_t)(u.w >> 16)};
            #pragma unroll
            for (int j = 0; j < 8; ++j) Kt[(mo * 8 + j) * 72 + t] = e[j];
        }
        const ushort_t* vr = &Vb[(c * CT + t) * DMODEL + h * DH];
        #pragma unroll
        for (int it = 0; it < 2; ++it) {
            int dd = it * 4 + g;
            uint4 u = *(const uint4*)&vr[dd * 8];
            ushort_t e[8] = {(ushort_t)(u.x & 0xffff), (ushort_t)(u.x >> 16),
                             (ushort_t)(u.y & 0xffff), (ushort_t)(u.y >> 16),
                             (ushort_t)(u.z & 0xffff), (ushort_t)(u.z >> 16),
                             (ushort_t)(u.w & 0xffff), (ushort_t)(u.w >> 16)};
            #pragma unroll
            for (int j = 0; j < 8; ++j) Vt[(dd * 8 + j) * 72 + t] = e[j];
        }
        if (g == 0) Vt[64 * 72 + t] = 0x3F80;     // bf16 1.0
        if (g == 1) {
            #pragma unroll
            for (int r = 65; r < 80; ++r) Vt[r * 72 + t] = 0;
        }
    }
    __syncthreads();

    f32x4 acc[2][5];
    const f32x4 z4 = {0.f, 0.f, 0.f, 0.f};
    #pragma unroll
    for (int i = 0; i < 2; ++i)
        #pragma unroll
        for (int j = 0; j < 5; ++j) acc[i][j] = z4;
    #pragma unroll
    for (int kt = 0; kt < 2; ++kt) {
        bf16x8 af[2], bfr[5];
        #pragma unroll
        for (int i = 0; i < 2; ++i)
            af[i] = *(const bf16x8*)&Kt[(wave * 32 + i * 16 + l15) * 72 + kt * 32 + quad * 8];
        #pragma unroll
        for (int j = 0; j < 5; ++j)
            bfr[j] = *(const bf16x8*)&Vt[(j * 16 + l15) * 72 + kt * 32 + quad * 8];
        #pragma unroll
        for (int i = 0; i < 2; ++i)
            #pragma unroll
            for (int j = 0; j < 5; ++j)
                acc[i][j] = __builtin_amdgcn_mfma_f32_16x16x32_bf16(af[i], bfr[j], acc[i][j], 0, 0, 0);
    }
    ushort_t* outS = SSb + (h * NC + c) * 8192;
    #pragma unroll
    for (int i = 0; i < 2; ++i)
        #pragma unroll
        for (int reg = 0; reg < 4; ++reg) {
            int m = wave * 32 + i * 16 + quad * 4 + reg;
            #pragma unroll
            for (int j = 0; j < 4; ++j)
                outS[m * 64 + j * 16 + l15] = f2bf(acc[i][j][reg]);
            if (l15 == 0) SSz[(h * NC + c) * M + m] = acc[i][4][reg];
        }
}

// ------- in-place exclusive prefix over chunks (batched loads) --------------
__global__ __launch_bounds__(256) void prefix_kernel(
    ushort_t* __restrict__ SSb, float* __restrict__ SSz)
{
    const int h = blockIdx.y;
    if (blockIdx.x == 32) {
        const int m = threadIdx.x;
        if (m < M) {
            float v[NC];
            #pragma unroll
            for (int c = 0; c < NC; ++c) v[c] = SSz[(h * NC + c) * M + m];
            float run = 0.f;
            #pragma unroll
            for (int c = 0; c < NC; ++c) {
                SSz[(h * NC + c) * M + m] = run;
                run += v[c];
            }
        }
        return;
    }
    const int idx = blockIdx.x * 256 + threadIdx.x;   // < 8192
    ushort_t v[NC];
    #pragma unroll
    for (int c = 0; c < NC; ++c) v[c] = SSb[(h * NC + c) * 8192 + idx];
    float run = 0.f;
    #pragma unroll
    for (int c = 0; c < NC; ++c) {
        SSb[(h * NC + c) * 8192 + idx] = f2bf(run);
        run += bf2f(v[c]);
    }
}

// ---------------- per-chunk causal kernel attention (MFMA) ------------------
// den = [Am|Q'] @ [ones;z] = output column 64 of the phase-2 MFMA.
__global__ __launch_bounds__(512) void attn_kernel(
    const ushort_t* __restrict__ QPb, const ushort_t* __restrict__ KPb,
    const ushort_t* __restrict__ Vb, const ushort_t* __restrict__ SSb,
    const float* __restrict__ SSz, ushort_t* __restrict__ ctxb)
{
    __shared__ ushort_t Qp[64 * 136];   // stride 136 bf16
    __shared__ ushort_t Kp[64 * 136];
    __shared__ ushort_t St[80 * 136];   // S^T [d][m]; row 64 = z
    __shared__ ushort_t Vt[80 * 72];    // V^T [d][t]; row 64 = ones
    __shared__ ushort_t Am[64 * 72];    // masked scores [row][col]
    __shared__ float den[CT];
    const int tid = threadIdx.x;
    const int c = blockIdx.x, h = blockIdx.y;
    const int lane = tid & 63;
    const int wave = tid >> 6;
    const int i  = wave & 3;            // rows tile (16 rows)
    const int nh = wave >> 2;           // cols half (32 cols)
    const int quad = lane >> 4;
    const int l15  = lane & 15;

    // ---- stage ----
    for (int t = tid; t < 2048; t += 512) {          // Qp/Kp
        int mat = t >> 10, r = (t >> 4) & 63, c8 = t & 15;
        const ushort_t* src = mat ? KPb : QPb;
        uint4 u = *(const uint4*)&src[((h * L) + c * CT + r) * M + c8 * 8];
        ushort_t* dst = mat ? Kp : Qp;
        *(uint4*)&dst[r * 136 + c8 * 8] = u;
    }
    {   // Vt: transpose V 64x64 bf16
        int t = tid & 63, dg = tid >> 6;
        uint4 u = *(const uint4*)&Vb[(c * CT + t) * DMODEL + h * DH + dg * 8];
        ushort_t e[8] = {(ushort_t)(u.x & 0xffff), (ushort_t)(u.x >> 16),
                         (ushort_t)(u.y & 0xffff), (ushort_t)(u.y >> 16),
                         (ushort_t)(u.z & 0xffff), (ushort_t)(u.z >> 16),
                         (ushort_t)(u.w & 0xffff), (ushort_t)(u.w >> 16)};
        #pragma unroll
        for (int j = 0; j < 8; ++j) Vt[(dg * 8 + j) * 72 + t] = e[j];
    }
    {   // St[d][m] from S[m][d] (transpose-scatter, lanes along m -> free)
        const ushort_t* ssb = SSb + (long)(h * NC + c) * 8192;
        int m = tid & 127, dg = tid >> 7;    // dg 0..3
        #pragma unroll
        for (int it = 0; it < 2; ++it) {
            int dd = it * 4 + dg;            // d-octet 0..7
            uint4 u = *(const uint4*)&ssb[m * 64 + dd * 8];
            ushort_t e[8] = {(ushort_t)(u.x & 0xffff), (ushort_t)(u.x >> 16),
                             (ushort_t)(u.y & 0xffff), (ushort_t)(u.y >> 16),
                             (ushort_t)(u.z & 0xffff), (ushort_t)(u.z >> 16),
                             (ushort_t)(u.w & 0xffff), (ushort_t)(u.w >> 16)};
            #pragma unroll
            for (int j = 0; j < 8; ++j) St[(dd * 8 + j) * 136 + m] = e[j];
        }
    }
    if (tid < 128) St[64 * 136 + tid] = f2bf(SSz[(h * NC + c) * M + tid]);  // z row
    if (tid >= 128 && tid < 192) Vt[64 * 72 + (tid - 128)] = 0x3F80;        // ones
    for (int t = tid; t < 15 * 136; t += 512) St[65 * 136 + t] = 0;         // pad
    for (int t = tid; t < 15 * 72; t += 512)  Vt[65 * 72 + t] = 0;
    __syncthreads();

    // ---- phase 1: scores ----
    f32x4 acc1[2];
    const f32x4 z4 = {0.f, 0.f, 0.f, 0.f};
    acc1[0] = z4; acc1[1] = z4;
    #pragma unroll
    for (int kt = 0; kt < 4; ++kt) {
        bf16x8 af = *(const bf16x8*)&Qp[(i * 16 + l15) * 136 + kt * 32 + quad * 8];
        #pragma unroll
        for (int jt = 0; jt < 2; ++jt) {
            bf16x8 bf = *(const bf16x8*)&Kp[(nh * 32 + jt * 16 + l15) * 136 + kt * 32 + quad * 8];
            acc1[jt] = __builtin_amdgcn_mfma_f32_16x16x32_bf16(af, bf, acc1[jt], 0, 0, 0);
        }
    }
    #pragma unroll
    for (int jt = 0; jt < 2; ++jt) {
        int col = nh * 32 + jt * 16 + l15;
        #pragma unroll
        for (int reg = 0; reg < 4; ++reg) {
            int row = i * 16 + quad * 4 + reg;
            Am[row * 72 + col] = f2bf((col <= row) ? acc1[jt][reg] : 0.f);
        }
    }
    __syncthreads();

    // ---- phase 2: N = [Am|Q'] @ [V;S], den = column 64 ----
    f32x4 acc2[2], acc3;
    acc2[0] = z4; acc2[1] = z4; acc3 = z4;
    #pragma unroll
    for (int kt = 0; kt < 6; ++kt) {
        bf16x8 af = (kt < 2)
            ? *(const bf16x8*)&Am[(i * 16 + l15) * 72 + kt * 32 + quad * 8]
            : *(const bf16x8*)&Qp[(i * 16 + l15) * 136 + (kt - 2) * 32 + quad * 8];
        #pragma unroll
        for (int jt = 0; jt < 2; ++jt) {
            int n = nh * 32 + jt * 16 + l15;
            bf16x8 bf = (kt < 2)
                ? *(const bf16x8*)&Vt[n * 72 + kt * 32 + quad * 8]
                : *(const bf16x8*)&St[n * 136 + (kt - 2) * 32 + quad * 8];
            acc2[jt] = __builtin_amdgcn_mfma_f32_16x16x32_bf16(af, bf, acc2[jt], 0, 0, 0);
        }
        if (nh == 0) {
            bf16x8 bz = (kt < 2)
                ? *(const bf16x8*)&Vt[(64 + l15) * 72 + kt * 32 + quad * 8]
                : *(const bf16x8*)&St[(64 + l15) * 136 + (kt - 2) * 32 + quad * 8];
            acc3 = __builtin_amdgcn_mfma_f32_16x16x32_bf16(af, bz, acc3, 0, 0, 0);
        }
    }
    if (nh == 0 && l15 == 0) {
        #pragma unroll
        for (int reg = 0; reg < 4; ++reg)
            den[i * 16 + quad * 4 + reg] = acc3[reg];
    }
    __syncthreads();
    #pragma unroll
    for (int jt = 0; jt < 2; ++jt) {
        int d = nh * 32 + jt * 16 + l15;
        #pragma unroll
        for (int reg = 0; reg < 4; ++reg) {
            int row = i * 16 + quad * 4 + reg;
            ctxb[(c * CT + row) * DMODEL + h * DH + d] = f2bf(acc2[jt][reg] / (den[row] + DEPS));
        }
    }
}

extern "C" void kernel_launch(void* const* d_in, const int* in_sizes, int n_in,
                              void* d_out, int out_size, void* d_ws, size_t ws_size,
                              hipStream_t stream)
{
    const float* query = (const float*)d_in[0];
    const float* key_  = (const float*)d_in[1];
    const float* value = (const float*)d_in[2];
    const float* Wq = (const float*)d_in[3];
    const float* bq = (const float*)d_in[4];
    const float* Wk = (const float*)d_in[5];
    const float* bk = (const float*)d_in[6];
    const float* Wv = (const float*)d_in[7];
    const float* bv = (const float*)d_in[8];
    const float* Wo = (const float*)d_in[9];
    const float* bo = (const float*)d_in[10];
    const float* RF = (const float*)d_in[11];

    float* ws = (float*)d_ws;
    ushort_t* Qb  = (ushort_t*)(ws + OFF_QB);
    ushort_t* Kb  = (ushort_t*)(ws + OFF_KB);
    ushort_t* Vb  = (ushort_t*)(ws + OFF_VB);
    ushort_t* QPb = (ushort_t*)(ws + OFF_QPB);
    ushort_t* KPb = (ushort_t*)(ws + OFF_KPB);
    ushort_t* SSb = (ushort_t*)(ws + OFF_SSB);
    float* SSz    = ws + OFF_SSZ;
    ushort_t* CTXB = (ushort_t*)(ws + OFF_CTX);
    ushort_t* RFT = (ushort_t*)(ws + OFF_RFT);

    qkv_mfma_kernel<<<dim3(32, 4, 4), 256, 0, stream>>>(query, key_, value,
                                                        Wq, bq, Wk, bk, Wv, bv, RF,
                                                        Qb, Kb, Vb, RFT);
    primes_mfma_kernel<<<dim3(16, 8, 2), 256, 0, stream>>>(Qb, Kb, RFT, QPb, KPb);
    chunksum_mfma_kernel<<<dim3(NC, 8), 256, 0, stream>>>(KPb, Vb, SSb, SSz);
    prefix_kernel<<<dim3(33, 8), 256, 0, stream>>>(SSb, SSz);
    attn_kernel<<<dim3(NC, 8), 512, 0, stream>>>(QPb, KPb, Vb, SSb, SSz, CTXB);
    out_gemm_kernel<<<dim3(64, 4), 256, 0, stream>>>(CTXB, Wo, bo, (float*)d_out);
}